// Round 13
// baseline (911.643 us; speedup 1.0000x reference)
//
#include <hip/hip_runtime.h>
#include <hip/hip_bf16.h>
#include <hip/hip_fp16.h>
#include <math.h>

#define D 128

// problem sizes (fixed by reference)
#define NU 100000
#define NP 100000
#define NC 1000
#define NB 2000
#define NTOT 203000
#define EB 100000
#define ES 50000
#define ETOT 800000
#define NSEG 803000
#define NBLK 785          // ceil(NSEG/1024)

// ws layout (float offsets)
#define OFF_L    0            // 6448000 floats: low-rank accumulators
#define OFF_W0   6448000      // 10*3*128
#define OFF_BS   6451840      // 16 (bs[4])
#define OFF_WT   7251856      // 16384 floats: W_base^T
#define OFF_AT   7268240      // 8192 floats: A^T per phi
#define OFF_INT  7276432      // int region
#define OFF_XH   9682432      // __half region: x_user (12.8M halfs) + x_product (12.8M halfs)
// ints relative to (int*)(wsf+OFF_INT):
//   counts @ 0        (803000)
//   starts @ 803000   (803000)  -- after kscatter: segment END
//   srco   @ 1606000  (800000)  -- src | o<<17 | et<<19, CSR order (o = beta for behavioral)

// per-edge-type metadata
__constant__ int c_srcT[10]   = {0,0,0,1,1,1,1,2,1,3};
__constant__ int c_phi [10]   = {0,0,0,1,1,1,1,2,1,3};
__constant__ int c_beta[10]   = {0,1,2,0,1,2,-1,-1,-1,-1};
__constant__ int c_E   [10]   = {EB,EB,EB,EB,EB,EB,ES,ES,ES,ES};
__constant__ int c_moff[10]   = {0,100000,200000,300000,400000,500000,600000,601000,701000,703000};

__constant__ int g_nGrp[4]    = {1,3,1,1};
__constant__ int g_Loff[4][3] = {{1600000,0,0},{0,3216000,4848000},{3200000,0,0},{4816000,0,0}};
__constant__ int g_ai[4][3]   = {{1,0,0},{0,2,3},{1,0,0},{1,0,0}};

// k4 fused-launch block ranges: U 782, P 782, C 8, B 16
#define K4_BU 782
#define K4_BP 1564
#define K4_BC 1572
#define K4_BT 1588

struct Ptrs {
    const float* x[4];
    const int*   ei[10];
    const int*   attr[4];   // for edge types 6..9
};

__device__ __forceinline__ void decode_et(int eflat, int& et, int& le) {
    if (eflat < 600000) { et = eflat / 100000; le = eflat - et * 100000; }
    else { int r = eflat - 600000; int q = r / 50000; et = 6 + q; le = r - q * 50000; }
}

// sum across the 16-lane quarter-wave group
__device__ __forceinline__ float qsum(float v) {
    v += __shfl_xor(v, 1, 64);
    v += __shfl_xor(v, 2, 64);
    v += __shfl_xor(v, 4, 64);
    v += __shfl_xor(v, 8, 64);
    return v;
}

// load 8 floats of row `row`, chunk ln (fp32 table or fp16 cache)
template<int F16>
__device__ __forceinline__ void loadrow(const void* xs, int row, int ln, float4& A, float4& B) {
    if (F16) {
        const __half* p = (const __half*)xs + (size_t)row*D + ln*8;
        float4 raw = *(const float4*)p;            // 8 halfs = 16B
        const __half2* h = (const __half2*)&raw;
        float2 a = __half22float2(h[0]), b = __half22float2(h[1]);
        float2 c = __half22float2(h[2]), d = __half22float2(h[3]);
        A = make_float4(a.x, a.y, b.x, b.y);
        B = make_float4(c.x, c.y, d.x, d.y);
    } else {
        const float* p = (const float*)xs + (size_t)row*D + ln*8;
        A = *(const float4*)p; B = *(const float4*)(p+4);
    }
}

// ---------------- kxhalf: fp16 cache of x_user || x_product ----------------
__global__ __launch_bounds__(256) void kxhalf(const float* __restrict__ xu,
        const float* __restrict__ xp, __half* __restrict__ xh)
{
    int idx = blockIdx.x*256 + threadIdx.x;     // each handles 8 elements
    if (idx >= 3200000) return;
    const float* src = (idx < 1600000) ? (xu + (size_t)idx*8)
                                       : (xp + (size_t)(idx-1600000)*8);
    float4 a = *(const float4*)src, b = *(const float4*)(src+4);
    float4 outv;
    __half2* q = (__half2*)&outv;
    q[0] = __floats2half2_rn(a.x, a.y);
    q[1] = __floats2half2_rn(a.z, a.w);
    q[2] = __floats2half2_rn(b.x, b.y);
    q[3] = __floats2half2_rn(b.z, b.w);
    *(float4*)(xh + (size_t)idx*8) = outv;
}

// ---------------- K0: w0 tables + bs ----------------
__global__ void k0_tables(const float* __restrict__ Wb, const float* __restrict__ A,
                          const float* __restrict__ B, const float* __restrict__ behW,
                          const float* __restrict__ a_att,
                          float* __restrict__ w0, float* __restrict__ bs_out)
{
    __shared__ float a0[128];
    __shared__ float c0[128];
    __shared__ float g0[4][16];
    int t = threadIdx.x;
    if (t < 128) a0[t] = a_att[t];
    __syncthreads();
    if (t < 128) {
        float s0=0.f;
        for (int j=0;j<128;j++) s0 += Wb[j*128+t]*a0[j];
        c0[t]=s0;
    } else if (t < 192) {
        int q=t-128, p=q>>4, r=q&15;
        float s0=0.f;
        for (int i=0;i<128;i++) s0 += A[p*2048+i*16+r]*a0[i];
        g0[p][r]=s0;
    } else if (t < 196) {
        int b=t-192; float s=0.f;
        for (int i=0;i<128;i++) s += behW[b*128+i]*a_att[384+i];
        bs_out[b]=s;
    }
    __syncthreads();
    if (t < 128) {
        for (int et=0; et<10; ++et) {
            int phi=c_phi[et], beta=c_beta[et];
            if (beta >= 0) {
                float s0=c0[t];
                for (int r=0;r<16;r++) s0 += B[beta*2048+t*16+r]*g0[phi][r];
                w0[et*384+t]=s0; w0[et*384+128+t]=s0; w0[et*384+256+t]=s0;
            } else {
                for (int o=0;o<3;o++){
                    float s0=c0[t];
                    for (int r=0;r<16;r++) s0 += B[o*2048+t*16+r]*g0[phi][r];
                    w0[et*384+o*128+t]=s0;
                }
            }
        }
    }
}

// ---------------- ktrans: W_base^T and A^T precompute ----------------
__global__ __launch_bounds__(256) void ktrans(const float* __restrict__ Wb,
        const float* __restrict__ A, float* __restrict__ WbT, float* __restrict__ AT)
{
    int idx = blockIdx.x*256 + threadIdx.x;
    if (idx < 16384) { int i = idx>>7, j = idx&127; WbT[i*128+j] = Wb[j*128+i]; }
    int idx2 = idx - 16384;
    if (idx2 >= 0 && idx2 < 8192) {
        int p = idx2>>11, rem = idx2&2047, r = rem>>7, j = rem&127;
        AT[idx2] = A[p*2048 + j*16 + r];
    }
}

// ---------------- CSR build ----------------
__global__ __launch_bounds__(256) void khist(Ptrs P, int* __restrict__ counts)
{
    int eflat = blockIdx.x*256 + threadIdx.x;
    if (eflat >= ETOT) return;
    int et, le; decode_et(eflat, et, le);
    int dst = P.ei[et][c_E[et] + le];
    atomicAdd(&counts[c_moff[et] + dst], 1);
}

__global__ __launch_bounds__(256) void kscan1(const int* __restrict__ cnt,
                                              int* __restrict__ st, int* __restrict__ bsums)
{
    __shared__ int lds[256];
    int t = threadIdx.x, b = blockIdx.x;
    int base = b*1024 + t*4;
    int v0 = (base   < NSEG) ? cnt[base]   : 0;
    int v1 = (base+1 < NSEG) ? cnt[base+1] : 0;
    int v2 = (base+2 < NSEG) ? cnt[base+2] : 0;
    int v3 = (base+3 < NSEG) ? cnt[base+3] : 0;
    int s = v0+v1+v2+v3;
    lds[t] = s; __syncthreads();
    for (int off=1; off<256; off<<=1){
        int xv = (t>=off) ? lds[t-off] : 0;
        __syncthreads();
        lds[t] += xv;
        __syncthreads();
    }
    int incl = lds[t];
    int p = incl - s;
    if (t==255) bsums[b] = incl;
    if (base   < NSEG) st[base]   = p; p += v0;
    if (base+1 < NSEG) st[base+1] = p; p += v1;
    if (base+2 < NSEG) st[base+2] = p; p += v2;
    if (base+3 < NSEG) st[base+3] = p;
}

__global__ __launch_bounds__(256) void kscan2(int* __restrict__ bsums)
{
    __shared__ int lds[256];
    int t = threadIdx.x;
    int base = t*4;
    int v0 = (base   < NBLK) ? bsums[base]   : 0;
    int v1 = (base+1 < NBLK) ? bsums[base+1] : 0;
    int v2 = (base+2 < NBLK) ? bsums[base+2] : 0;
    int v3 = (base+3 < NBLK) ? bsums[base+3] : 0;
    int s = v0+v1+v2+v3;
    lds[t] = s; __syncthreads();
    for (int off=1; off<256; off<<=1){
        int xv = (t>=off) ? lds[t-off] : 0;
        __syncthreads();
        lds[t] += xv;
        __syncthreads();
    }
    int p = lds[t] - s;
    if (base   < NBLK) bsums[base]   = p; p += v0;
    if (base+1 < NBLK) bsums[base+1] = p; p += v1;
    if (base+2 < NBLK) bsums[base+2] = p; p += v2;
    if (base+3 < NBLK) bsums[base+3] = p;
}

__global__ __launch_bounds__(256) void kscan3(int* __restrict__ st, const int* __restrict__ bsums)
{
    int t = threadIdx.x, b = blockIdx.x;
    int add = bsums[b];
    int base = b*1024 + t*4;
    #pragma unroll
    for (int j=0;j<4;j++)
        if (base+j < NSEG) st[base+j] += add;
}

__global__ __launch_bounds__(256) void kscatter(Ptrs P, int* __restrict__ st, int* __restrict__ srco)
{
    int eflat = blockIdx.x*256 + threadIdx.x;
    if (eflat >= ETOT) return;
    int et, le; decode_et(eflat, et, le);
    const int* ei = P.ei[et];
    int E = c_E[et];
    int src = ei[le], dst = ei[E+le];
    int o;
    if (et >= 6) { int a = P.attr[et-6][le]; o = min(max(a,0),2); }
    else o = c_beta[et];
    int pos = atomicAdd(&st[c_moff[et] + dst], 1);
    srco[pos] = src | (o<<17) | (et<<19);
}
// after kscatter: st[seg] == segment end; start = st[seg] - counts[seg]

// ---------------- kagg_beh: behavioral edges (et0-5), wave per node -------------------
// R9 structure (proven best) + templated fp16 x-gathers.
template<int F16>
__global__ __launch_bounds__(256) void kagg_beh(Ptrs P,
        const int* __restrict__ starts, const int* __restrict__ counts,
        const int* __restrict__ srco,
        const float* __restrict__ w0, const float* __restrict__ Bm,
        float* __restrict__ Sout, float* __restrict__ Lb, int nWaves,
        const void* __restrict__ gxu, const void* __restrict__ gxp)
{
    int lane = threadIdx.x & 63;
    int wv = (blockIdx.x * 256 + threadIdx.x) >> 6;
    int grp = lane >> 4, ln = lane & 15;

    for (int nid = wv; nid < NU + NP; nid += nWaves) {
        int T = (nid < NU) ? 0 : 1;
        int n0 = (T == 0) ? nid : nid - NU;
        int etBase = (T == 0) ? 3 : 0;
        const void* xs = (T == 0) ? gxp : gxu;   // user dst gathers product rows, vice versa

        // upfront parallel seginfo (moff contiguous: seg + s*100000)
        int sgA = c_moff[etBase] + n0;
        int cnt0 = counts[sgA],        cnt1 = counts[sgA+100000], cnt2 = counts[sgA+200000];
        int sa0  = starts[sgA]-cnt0,   sa1  = starts[sgA+100000]-cnt1, sa2 = starts[sgA+200000]-cnt2;
        // upfront parallel first-quad srco
        int sv1 = (grp < cnt1) ? srco[sa1+grp] : 0;
        int sv2 = (grp < cnt2) ? srco[sa2+grp] : 0;
        // prefetch x first-quad for segment 0
        float4 pA = make_float4(0.f,0.f,0.f,0.f), pB = pA;
        if (grp < cnt0) {
            int sv0 = srco[sa0+grp];
            loadrow<F16>(xs, sv0 & 0x1FFFF, ln, pA, pB);
        }

        float Stot[8] = {0,0,0,0,0,0,0,0};
        float Lq0=0.f, Lq1=0.f, Lq2=0.f, Lq3=0.f;

        for (int s=0; s<3; ++s) {
            int cnt = (s==0)?cnt0:((s==1)?cnt1:cnt2);
            int st0 = (s==0)?sa0:((s==1)?sa1:sa2);
            float4 cA = pA, cB = pB;
            // rolling prefetch: next segment's first-quad x (srco already in sv1/sv2)
            pA = make_float4(0.f,0.f,0.f,0.f); pB = pA;
            if (s == 0) {
                if (grp < cnt1) loadrow<F16>(xs, sv1 & 0x1FFFF, ln, pA, pB);
            } else if (s == 1) {
                if (grp < cnt2) loadrow<F16>(xs, sv2 & 0x1FFFF, ln, pA, pB);
            }
            if (cnt == 0) continue;
            int et = etBase + s;
            const float* wq = w0 + et*384 + ln*8;
            float4 wA = *(const float4*)wq, wB = *(const float4*)(wq+4);

            float ssum = 0.f;
            float SA[8] = {0,0,0,0,0,0,0,0};

            for (int k0=0; k0<cnt; k0+=4) {
                bool act = (k0+grp) < cnt;
                if (k0 > 0) {
                    cA = make_float4(0.f,0.f,0.f,0.f); cB = cA;
                    if (act) {
                        int sv = srco[st0+k0+grp];
                        loadrow<F16>(xs, sv & 0x1FFFF, ln, cA, cB);
                    }
                }
                float d = cA.x*wA.x + cA.y*wA.y + cA.z*wA.z + cA.w*wA.w
                        + cB.x*wB.x + cB.y*wB.y + cB.z*wB.z + cB.w*wB.w;
                d = qsum(d);
                float wg = act ? __expf(d) : 0.f;   // no-max softmax (shift-invariant)
                ssum += wg;
                SA[0]+=wg*cA.x; SA[1]+=wg*cA.y; SA[2]+=wg*cA.z; SA[3]+=wg*cA.w;
                SA[4]+=wg*cB.x; SA[5]+=wg*cB.y; SA[6]+=wg*cB.z; SA[7]+=wg*cB.w;
            }
            // cross-slot totals
            ssum += __shfl_xor(ssum, 16, 64);
            ssum += __shfl_xor(ssum, 32, 64);
            float inv = 1.f/(ssum + 1e-16f);
            #pragma unroll
            for (int j=0;j<8;j++){ SA[j] += __shfl_xor(SA[j],16,64); SA[j] += __shfl_xor(SA[j],32,64); }
            #pragma unroll
            for (int j=0;j<8;j++) Stot[j] += SA[j]*inv;

            // B[beta=s]^T SA : cols grp*4..+3, rows ln*8..+7
            const float* Bp = Bm + s*2048 + grp*4;
            float p0=0.f,p1=0.f,p2=0.f,p3=0.f;
            #pragma unroll
            for (int j=0;j<8;j++){
                float4 b4 = *(const float4*)(Bp + (ln*8+j)*16);
                float v = SA[j];
                p0+=v*b4.x; p1+=v*b4.y; p2+=v*b4.z; p3+=v*b4.w;
            }
            Lq0 += qsum(p0)*inv; Lq1 += qsum(p1)*inv;
            Lq2 += qsum(p2)*inv; Lq3 += qsum(p3)*inv;
        }

        if (grp == 0) {
            float* Srow = Sout + (size_t)nid*D + ln*8;
            *(float4*)Srow     = make_float4(Stot[0],Stot[1],Stot[2],Stot[3]);
            *(float4*)(Srow+4) = make_float4(Stot[4],Stot[5],Stot[6],Stot[7]);
        }
        if (ln < 4) {
            float v = (ln==0)?Lq0:((ln==1)?Lq1:((ln==2)?Lq2:Lq3));
            int loff = (T==0) ? 1600000 : 0;
            Lb[loff + (size_t)n0*16 + grp*4 + ln] = v;
        }
    }
}

// ---------------- str_seg_prod: one structural segment of a product ------------------
// srcs are cat/brand tables (fp32, small, L2-hot).
__device__ __forceinline__ void str_seg_prod(int cnt, int st0, int hv,
        const int* __restrict__ srco, const float* __restrict__ xs,
        const float* __restrict__ wbase, float bs0, float bs1, float bs2,
        const float* __restrict__ Bm, int grp, int ln,
        float Stot[8], float* __restrict__ Lrow)
{
    if (cnt == 0) return;
    float ssum = 0.f;
    float SA[8]={0,0,0,0,0,0,0,0}, SB[8]={0,0,0,0,0,0,0,0}, SC[8]={0,0,0,0,0,0,0,0};
    int fa=0, fb=0, fc=0;

    for (int k0=0; k0<cnt; k0+=4) {
        bool act = (k0+grp) < cnt;
        int sv = (k0 == 0) ? hv : (act ? srco[st0+k0+grp] : 0);
        int o = (sv>>17)&3;
        float4 hA = make_float4(0.f,0.f,0.f,0.f), hB = hA;
        if (act) {
            const float* q = xs + (size_t)(sv & 0x1FFFF)*D + ln*8;
            hA = *(const float4*)q; hB = *(const float4*)(q+4);
        }
        const float* wq = wbase + o*128 + ln*8;
        float4 wA = *(const float4*)wq, wB = *(const float4*)(wq+4);
        float d = hA.x*wA.x + hA.y*wA.y + hA.z*wA.z + hA.w*wA.w
                + hB.x*wB.x + hB.y*wB.y + hB.z*wB.z + hB.w*wB.w;
        d = qsum(d);
        float wg = act ? __expf(d + ((o==0)?bs0:((o==1)?bs1:bs2))) : 0.f;
        ssum += wg;
        fa |= (int)(act && (o==0)); fb |= (int)(act && (o==1)); fc |= (int)(act && (o==2));
        float wg0=(o==0)?wg:0.f, wg1=(o==1)?wg:0.f, wg2=(o==2)?wg:0.f;
        #pragma unroll
        for (int j=0;j<8;j++){
            float hj = (j==0)?hA.x:(j==1)?hA.y:(j==2)?hA.z:(j==3)?hA.w:
                       (j==4)?hB.x:(j==5)?hB.y:(j==6)?hB.z:hB.w;
            SA[j] += wg0*hj; SB[j] += wg1*hj; SC[j] += wg2*hj;
        }
    }

    ssum += __shfl_xor(ssum, 16, 64);
    ssum += __shfl_xor(ssum, 32, 64);
    float inv = 1.f/(ssum + 1e-16f);

    int anyA = __any(fa), anyB = __any(fb), anyC = __any(fc);
    if (anyA) {
        #pragma unroll
        for (int j=0;j<8;j++){ SA[j] += __shfl_xor(SA[j],16,64); SA[j] += __shfl_xor(SA[j],32,64); }
    }
    if (anyB) {
        #pragma unroll
        for (int j=0;j<8;j++){ SB[j] += __shfl_xor(SB[j],16,64); SB[j] += __shfl_xor(SB[j],32,64); }
    }
    if (anyC) {
        #pragma unroll
        for (int j=0;j<8;j++){ SC[j] += __shfl_xor(SC[j],16,64); SC[j] += __shfl_xor(SC[j],32,64); }
    }
    #pragma unroll
    for (int j=0;j<8;j++) Stot[j] += (SA[j]+SB[j]+SC[j])*inv;

    float p0=0.f,p1=0.f,p2=0.f,p3=0.f;
    if (anyA) {
        const float* Bp = Bm + grp*4;
        #pragma unroll
        for (int j=0;j<8;j++){
            float4 b4 = *(const float4*)(Bp + (ln*8+j)*16);
            float v = SA[j];
            p0+=v*b4.x; p1+=v*b4.y; p2+=v*b4.z; p3+=v*b4.w;
        }
    }
    if (anyB) {
        const float* Bp = Bm + 2048 + grp*4;
        #pragma unroll
        for (int j=0;j<8;j++){
            float4 b4 = *(const float4*)(Bp + (ln*8+j)*16);
            float v = SB[j];
            p0+=v*b4.x; p1+=v*b4.y; p2+=v*b4.z; p3+=v*b4.w;
        }
    }
    if (anyC) {
        const float* Bp = Bm + 4096 + grp*4;
        #pragma unroll
        for (int j=0;j<8;j++){
            float4 b4 = *(const float4*)(Bp + (ln*8+j)*16);
            float v = SC[j];
            p0+=v*b4.x; p1+=v*b4.y; p2+=v*b4.z; p3+=v*b4.w;
        }
    }
    p0 = qsum(p0)*inv; p1 = qsum(p1)*inv; p2 = qsum(p2)*inv; p3 = qsum(p3)*inv;
    if (ln < 4) {
        float v = (ln==0)?p0:((ln==1)?p1:((ln==2)?p2:p3));
        Lrow[grp*4 + ln] = v;
    }
}

// ---------------- kagg_str: structural edges (et6-9), wave per node -------------------
// Products: skip both-empty. Cat/brand: fp16 product gathers, depth-1 quad prefetch.
template<int F16>
__global__ __launch_bounds__(256) void kagg_str(Ptrs P,
        const int* __restrict__ starts, const int* __restrict__ counts,
        const int* __restrict__ srco,
        const float* __restrict__ w0, const float* __restrict__ bs,
        const float* __restrict__ Bm,
        float* __restrict__ Sout, float* __restrict__ Lb, int nWaves,
        const void* __restrict__ gxp)
{
    int lane = threadIdx.x & 63;
    int wv = (blockIdx.x * 256 + threadIdx.x) >> 6;
    int grp = lane >> 4, ln = lane & 15;
    float bs0 = bs[0], bs1 = bs[1], bs2 = bs[2];

    for (int id = wv; id < NP + NC + NB; id += nWaves) {
        if (id < NP) {
            int n0 = id;
            int seg7 = 601000 + n0, seg9 = 703000 + n0;
            int cnt7 = counts[seg7], cnt9 = counts[seg9];
            if ((cnt7 | cnt9) == 0) continue;          // no RMW; L memset covers
            int st7 = starts[seg7] - cnt7, st9 = starts[seg9] - cnt9;
            int hv7 = (grp < cnt7) ? srco[st7+grp] : 0;
            int hv9 = (grp < cnt9) ? srco[st9+grp] : 0;

            float Stot[8] = {0,0,0,0,0,0,0,0};
            str_seg_prod(cnt7, st7, hv7, srco, P.x[2], w0 + 7*384,
                         bs0, bs1, bs2, Bm, grp, ln, Stot,
                         Lb + 3216000 + (size_t)n0*16);
            str_seg_prod(cnt9, st9, hv9, srco, P.x[3], w0 + 9*384,
                         bs0, bs1, bs2, Bm, grp, ln, Stot,
                         Lb + 4848000 + (size_t)n0*16);

            if (grp == 0) {
                float* Srow = Sout + (size_t)(100000+n0)*D + ln*8;
                float4 a = *(const float4*)Srow, b = *(const float4*)(Srow+4);
                *(float4*)Srow     = make_float4(a.x+Stot[0],a.y+Stot[1],a.z+Stot[2],a.w+Stot[3]);
                *(float4*)(Srow+4) = make_float4(b.x+Stot[4],b.y+Stot[5],b.z+Stot[6],b.w+Stot[7]);
            }
        } else {
            int T = (id < NP+NC) ? 2 : 3;
            int n0 = (T==2) ? (id-NP) : (id-(NP+NC));
            int et = (T==2) ? 6 : 8;
            int outRow = (T==2) ? (200000+n0) : (201000+n0);
            int seg = c_moff[et] + n0;
            int cnt = counts[seg];
            int st0 = starts[seg] - cnt;
            const float* wbase = w0 + et*384;

            float ssum = 0.f;
            float SA[8]={0,0,0,0,0,0,0,0}, SB[8]={0,0,0,0,0,0,0,0}, SC[8]={0,0,0,0,0,0,0,0};
            int fa=0, fb=0, fc=0;

            // depth-1 quad pipeline over product rows (fp16 when available)
            int sv = 0;
            float4 hA = make_float4(0.f,0.f,0.f,0.f), hB = hA;
            if (grp < cnt) {
                sv = srco[st0+grp];
                loadrow<F16>(gxp, sv & 0x1FFFF, ln, hA, hB);
            }
            for (int k0=0; k0<cnt; k0+=4) {
                int svn = 0;
                float4 nA = make_float4(0.f,0.f,0.f,0.f), nB = nA;
                if (k0+4+grp < cnt) {
                    svn = srco[st0+k0+4+grp];
                    loadrow<F16>(gxp, svn & 0x1FFFF, ln, nA, nB);
                }
                bool act = (k0+grp) < cnt;
                int o = (sv>>17)&3;
                const float* wq = wbase + o*128 + ln*8;
                float4 wA = *(const float4*)wq, wB = *(const float4*)(wq+4);
                float d = hA.x*wA.x + hA.y*wA.y + hA.z*wA.z + hA.w*wA.w
                        + hB.x*wB.x + hB.y*wB.y + hB.z*wB.z + hB.w*wB.w;
                d = qsum(d);
                float wg = act ? __expf(d + ((o==0)?bs0:((o==1)?bs1:bs2))) : 0.f;
                ssum += wg;
                fa |= (int)(act && (o==0)); fb |= (int)(act && (o==1)); fc |= (int)(act && (o==2));
                float wg0=(o==0)?wg:0.f, wg1=(o==1)?wg:0.f, wg2=(o==2)?wg:0.f;
                #pragma unroll
                for (int j=0;j<8;j++){
                    float hj = (j==0)?hA.x:(j==1)?hA.y:(j==2)?hA.z:(j==3)?hA.w:
                               (j==4)?hB.x:(j==5)?hB.y:(j==6)?hB.z:hB.w;
                    SA[j] += wg0*hj; SB[j] += wg1*hj; SC[j] += wg2*hj;
                }
                sv = svn; hA = nA; hB = nB;
            }

            ssum += __shfl_xor(ssum, 16, 64);
            ssum += __shfl_xor(ssum, 32, 64);
            float inv = 1.f/(ssum + 1e-16f);

            int anyA = __any(fa), anyB = __any(fb), anyC = __any(fc);
            if (anyA) {
                #pragma unroll
                for (int j=0;j<8;j++){ SA[j] += __shfl_xor(SA[j],16,64); SA[j] += __shfl_xor(SA[j],32,64); }
            }
            if (anyB) {
                #pragma unroll
                for (int j=0;j<8;j++){ SB[j] += __shfl_xor(SB[j],16,64); SB[j] += __shfl_xor(SB[j],32,64); }
            }
            if (anyC) {
                #pragma unroll
                for (int j=0;j<8;j++){ SC[j] += __shfl_xor(SC[j],16,64); SC[j] += __shfl_xor(SC[j],32,64); }
            }
            float Stot[8];
            #pragma unroll
            for (int j=0;j<8;j++) Stot[j] = (SA[j]+SB[j]+SC[j])*inv;

            float p0=0.f,p1=0.f,p2=0.f,p3=0.f;
            if (anyA) {
                const float* Bp = Bm + grp*4;
                #pragma unroll
                for (int j=0;j<8;j++){
                    float4 b4 = *(const float4*)(Bp + (ln*8+j)*16);
                    float v = SA[j];
                    p0+=v*b4.x; p1+=v*b4.y; p2+=v*b4.z; p3+=v*b4.w;
                }
            }
            if (anyB) {
                const float* Bp = Bm + 2048 + grp*4;
                #pragma unroll
                for (int j=0;j<8;j++){
                    float4 b4 = *(const float4*)(Bp + (ln*8+j)*16);
                    float v = SB[j];
                    p0+=v*b4.x; p1+=v*b4.y; p2+=v*b4.z; p3+=v*b4.w;
                }
            }
            if (anyC) {
                const float* Bp = Bm + 4096 + grp*4;
                #pragma unroll
                for (int j=0;j<8;j++){
                    float4 b4 = *(const float4*)(Bp + (ln*8+j)*16);
                    float v = SC[j];
                    p0+=v*b4.x; p1+=v*b4.y; p2+=v*b4.z; p3+=v*b4.w;
                }
            }
            p0 = qsum(p0)*inv; p1 = qsum(p1)*inv; p2 = qsum(p2)*inv; p3 = qsum(p3)*inv;

            int loff = (T==2) ? 3200000 : 4816000;
            if (ln < 4) {
                float v = (ln==0)?p0:((ln==1)?p1:((ln==2)?p2:p3));
                Lb[loff + (size_t)n0*16 + grp*4 + ln] = v;
            }
            if (grp == 0) {
                float* Srow = Sout + (size_t)outRow*D + ln*8;
                *(float4*)Srow     = make_float4(Stot[0],Stot[1],Stot[2],Stot[3]);
                *(float4*)(Srow+4) = make_float4(Stot[4],Stot[5],Stot[6],Stot[7]);
            }
        }
    }
}

// ---------------- K4 (fused): agg = W_base@S + sum A[p]@L_p, LN+ELU+residual ----------
__global__ __launch_bounds__(512, 1) void k4_final(Ptrs P,
        const float* __restrict__ WbT, const float* __restrict__ AT,
        const float* __restrict__ Lb,
        const float* __restrict__ gamma, const float* __restrict__ lbeta,
        float* __restrict__ out)
{
    __shared__ float st[128*132];   // S tile, stride 132
    __shared__ float wt[128*128];   // WbT tile: wt[i*128 + j]
    __shared__ float lt[128*52];    // L tile: lt[r*52 + pi*16 + k]
    int t = threadIdx.x;
    int b = blockIdx.x;
    int T, lb;
    if (b < K4_BU)      { T=0; lb=b; }
    else if (b < K4_BP) { T=1; lb=b-K4_BU; }
    else if (b < K4_BC) { T=2; lb=b-K4_BP; }
    else                { T=3; lb=b-K4_BC; }
    int r0 = lb*128;
    int rowStart = (T==0)?0:((T==1)?100000:((T==2)?200000:201000));
    int nRows    = (T==0)?NU:((T==1)?NP:((T==2)?NC:NB));
    const float* x = P.x[T];
    int nPairs = g_nGrp[T];

    for (int idx=t; idx<4096; idx+=512)
        *(float4*)&wt[idx*4] = *(const float4*)&WbT[idx*4];
    for (int idx=t; idx<4096; idx+=512){
        int r = idx>>5, i4 = idx&31;
        int lr = r0 + r;
        float4 v = (lr < nRows) ? *(const float4*)&out[(size_t)(rowStart+lr)*D + i4*4]
                                : make_float4(0.f,0.f,0.f,0.f);
        *(float4*)&st[r*132 + i4*4] = v;
    }
    for (int pi=0; pi<nPairs; ++pi){
        int lo = g_Loff[T][pi];
        int r = t>>2, q = t&3;
        int lr = r0 + r;
        float4 v = (lr < nRows) ? *(const float4*)&Lb[lo + (size_t)lr*16 + q*4]
                                : make_float4(0.f,0.f,0.f,0.f);
        *(float4*)&lt[r*52 + pi*16 + q*4] = v;
    }
    __syncthreads();

    int cg = t & 15, rg = t >> 4;
    float acc[4][8];
    #pragma unroll
    for (int a=0;a<4;a++)
        #pragma unroll
        for (int c=0;c<8;c++) acc[a][c]=0.f;

    for (int i4=0; i4<32; ++i4){
        float4 sv0 = *(const float4*)&st[(rg*4+0)*132 + i4*4];
        float4 sv1 = *(const float4*)&st[(rg*4+1)*132 + i4*4];
        float4 sv2 = *(const float4*)&st[(rg*4+2)*132 + i4*4];
        float4 sv3 = *(const float4*)&st[(rg*4+3)*132 + i4*4];
        #pragma unroll
        for (int q=0;q<4;q++){
            float4 wA = *(const float4*)&wt[(i4*4+q)*128 + cg*4];
            float4 wB = *(const float4*)&wt[(i4*4+q)*128 + 64 + cg*4];
            float sq[4];
            sq[0] = (q==0)?sv0.x:(q==1)?sv0.y:(q==2)?sv0.z:sv0.w;
            sq[1] = (q==0)?sv1.x:(q==1)?sv1.y:(q==2)?sv1.z:sv1.w;
            sq[2] = (q==0)?sv2.x:(q==1)?sv2.y:(q==2)?sv2.z:sv2.w;
            sq[3] = (q==0)?sv3.x:(q==1)?sv3.y:(q==2)?sv3.z:sv3.w;
            #pragma unroll
            for (int rr=0;rr<4;rr++){
                acc[rr][0] += sq[rr]*wA.x;
                acc[rr][1] += sq[rr]*wA.y;
                acc[rr][2] += sq[rr]*wA.z;
                acc[rr][3] += sq[rr]*wA.w;
                acc[rr][4] += sq[rr]*wB.x;
                acc[rr][5] += sq[rr]*wB.y;
                acc[rr][6] += sq[rr]*wB.z;
                acc[rr][7] += sq[rr]*wB.w;
            }
        }
    }

    for (int pi=0; pi<nPairs; ++pi){
        int ai = g_ai[T][pi];
        const float* Ap = AT + ai*2048;
        #pragma unroll 4
        for (int r=0;r<16;++r){
            float4 aA = *(const float4*)&Ap[r*128 + cg*4];
            float4 aB = *(const float4*)&Ap[r*128 + 64 + cg*4];
            float lv[4];
            #pragma unroll
            for (int rr=0;rr<4;rr++) lv[rr] = lt[(rg*4+rr)*52 + pi*16 + r];
            #pragma unroll
            for (int rr=0;rr<4;rr++){
                acc[rr][0] += lv[rr]*aA.x;
                acc[rr][1] += lv[rr]*aA.y;
                acc[rr][2] += lv[rr]*aA.z;
                acc[rr][3] += lv[rr]*aA.w;
                acc[rr][4] += lv[rr]*aB.x;
                acc[rr][5] += lv[rr]*aB.y;
                acc[rr][6] += lv[rr]*aB.z;
                acc[rr][7] += lv[rr]*aB.w;
            }
        }
    }

    int jA = cg*4, jB = 64 + cg*4;
    float4 gA = *(const float4*)&gamma[jA], gB = *(const float4*)&gamma[jB];
    float4 bA = *(const float4*)&lbeta[jA], bB = *(const float4*)&lbeta[jB];
    float gv[8] = {gA.x,gA.y,gA.z,gA.w,gB.x,gB.y,gB.z,gB.w};
    float bv[8] = {bA.x,bA.y,bA.z,bA.w,bB.x,bB.y,bB.z,bB.w};

    #pragma unroll
    for (int rr=0;rr<4;rr++){
        int lr = r0 + rg*4 + rr;
        float lsum=0.f, lsq=0.f;
        #pragma unroll
        for (int c=0;c<8;c++){ lsum += acc[rr][c]; lsq += acc[rr][c]*acc[rr][c]; }
        #pragma unroll
        for (int mm=1; mm<16; mm<<=1){ lsum += __shfl_xor(lsum,mm,64); lsq += __shfl_xor(lsq,mm,64); }
        if (lr >= nRows) continue;
        float mu = lsum*(1.f/128.f);
        float var = lsq*(1.f/128.f) - mu*mu;
        float rstd = rsqrtf(var + 1e-5f);
        const float* xr = x + (size_t)lr*D;
        float4 xA = *(const float4*)(xr+jA), xB = *(const float4*)(xr+jB);
        float xv[8] = {xA.x,xA.y,xA.z,xA.w,xB.x,xB.y,xB.z,xB.w};
        float ov[8];
        #pragma unroll
        for (int c=0;c<8;c++){
            float hn = (acc[rr][c]-mu)*rstd*gv[c] + bv[c];
            float z = hn + xv[c];
            ov[c] = z > 0.f ? z : expm1f(z);
        }
        float* orow = out + (size_t)(rowStart+lr)*D;
        *(float4*)(orow+jA) = make_float4(ov[0],ov[1],ov[2],ov[3]);
        *(float4*)(orow+jB) = make_float4(ov[4],ov[5],ov[6],ov[7]);
    }
}

extern "C" void kernel_launch(void* const* d_in, const int* in_sizes, int n_in,
                              void* d_out, int out_size, void* d_ws, size_t ws_size,
                              hipStream_t stream)
{
    (void)in_sizes; (void)n_in; (void)out_size;
    Ptrs P;
    P.x[0] = (const float*)d_in[0];   // x_user
    P.x[1] = (const float*)d_in[1];   // x_product
    P.x[2] = (const float*)d_in[2];   // x_category
    P.x[3] = (const float*)d_in[3];   // x_brand
    P.ei[0] = (const int*)d_in[4];    // view
    P.ei[1] = (const int*)d_in[5];    // cart
    P.ei[2] = (const int*)d_in[6];    // purchase
    P.ei[3] = (const int*)d_in[7];    // rev_view
    P.ei[4] = (const int*)d_in[8];    // rev_cart
    P.ei[5] = (const int*)d_in[9];    // rev_purchase
    P.ei[6] = (const int*)d_in[10];   // belongs_to
    P.attr[0] = (const int*)d_in[11];
    P.ei[7] = (const int*)d_in[12];   // contains
    P.attr[1] = (const int*)d_in[13];
    P.ei[8] = (const int*)d_in[14];   // producedBy
    P.attr[2] = (const int*)d_in[15];
    P.ei[9] = (const int*)d_in[16];   // brands
    P.attr[3] = (const int*)d_in[17];
    const float* Wb    = (const float*)d_in[18];
    const float* A     = (const float*)d_in[19];
    const float* B     = (const float*)d_in[20];
    const float* behW  = (const float*)d_in[22];
    const float* a_att = (const float*)d_in[23];
    const float* gamma = (const float*)d_in[24];
    const float* lbeta = (const float*)d_in[25];
    float* wsf = (float*)d_ws;
    float* out = (float*)d_out;

    int* ip     = (int*)(wsf + OFF_INT);
    int* counts = ip;
    int* starts = ip + 803000;
    int* srco   = ip + 1606000;
    int* bsums  = (int*)wsf;          // overlays product L-group0 (fully rewritten by kagg_beh)

    const size_t F16_NEED = ((size_t)OFF_XH + 12800000) * 4;   // ~90 MB
    bool use16 = ws_size >= F16_NEED;
    __half* xh = (__half*)(wsf + OFF_XH);

    hipMemsetAsync(counts, 0, (size_t)NSEG*sizeof(int), stream);
    // zero only L regions that may be skipped (product structural groups; brand rewritten anyway)
    hipMemsetAsync(wsf + 3216000, 0, (size_t)(6448000-3216000)*sizeof(float), stream);

    k0_tables<<<1, 256, 0, stream>>>(Wb, A, B, behW, a_att, wsf+OFF_W0, wsf+OFF_BS);
    ktrans<<<96, 256, 0, stream>>>(Wb, A, wsf+OFF_WT, wsf+OFF_AT);
    if (use16) kxhalf<<<12500, 256, 0, stream>>>(P.x[0], P.x[1], xh);
    khist<<<3125, 256, 0, stream>>>(P, counts);
    kscan1<<<NBLK, 256, 0, stream>>>(counts, starts, bsums);
    kscan2<<<1, 256, 0, stream>>>(bsums);
    kscan3<<<NBLK, 256, 0, stream>>>(starts, bsums);
    kscatter<<<3125, 256, 0, stream>>>(P, starts, srco);

    if (use16) {
        kagg_beh<1><<<4096, 256, 0, stream>>>(P, starts, counts, srco,
                                              wsf+OFF_W0, B, out, wsf+OFF_L, 4096*4,
                                              (const void*)xh, (const void*)(xh + 12800000));
        kagg_str<1><<<1024, 256, 0, stream>>>(P, starts, counts, srco,
                                              wsf+OFF_W0, wsf+OFF_BS, B, out, wsf+OFF_L, 1024*4,
                                              (const void*)(xh + 12800000));
    } else {
        kagg_beh<0><<<4096, 256, 0, stream>>>(P, starts, counts, srco,
                                              wsf+OFF_W0, B, out, wsf+OFF_L, 4096*4,
                                              (const void*)P.x[0], (const void*)P.x[1]);
        kagg_str<0><<<1024, 256, 0, stream>>>(P, starts, counts, srco,
                                              wsf+OFF_W0, wsf+OFF_BS, B, out, wsf+OFF_L, 1024*4,
                                              (const void*)P.x[1]);
    }

    k4_final<<<K4_BT, 512, 0, stream>>>(P, wsf+OFF_WT, wsf+OFF_AT, wsf+OFF_L,
                                        gamma, lbeta, out);
}

// Round 14
// 887.530 us; speedup vs baseline: 1.0272x; 1.0272x over previous
//
#include <hip/hip_runtime.h>
#include <hip/hip_bf16.h>
#include <math.h>

#define D 128

// problem sizes (fixed by reference)
#define NU 100000
#define NP 100000
#define NC 1000
#define NB 2000
#define NTOT 203000
#define EB 100000
#define ES 50000
#define ETOT 800000
#define NSEG 803000
#define NBLK 785          // ceil(NSEG/1024)
#define NID_ALL 303000    // 200000 beh nodes + 100000 prod-str + 1000 cat + 2000 brand

// ws layout (float offsets)
#define OFF_L    0            // 6448000 floats: low-rank accumulators
#define OFF_W0   6448000      // 10*3*128
#define OFF_BS   6451840      // 16 (bs[4])
#define OFF_WT   7251856      // 16384 floats: W_base^T
#define OFF_AT   7268240      // 8192 floats: A^T per phi
#define OFF_INT  7276432      // int region
#define OFF_S2   9682432      // 12800000 floats: product structural S contributions
// ints relative to (int*)(wsf+OFF_INT):
//   counts @ 0        (803000)
//   starts @ 803000   (803000)  -- after kscatter: segment END
//   srco   @ 1606000  (800000)  -- src | o<<17 | et<<19, CSR order (o = beta for behavioral)

// per-edge-type metadata
__constant__ int c_srcT[10]   = {0,0,0,1,1,1,1,2,1,3};
__constant__ int c_phi [10]   = {0,0,0,1,1,1,1,2,1,3};
__constant__ int c_beta[10]   = {0,1,2,0,1,2,-1,-1,-1,-1};
__constant__ int c_E   [10]   = {EB,EB,EB,EB,EB,EB,ES,ES,ES,ES};
__constant__ int c_moff[10]   = {0,100000,200000,300000,400000,500000,600000,601000,701000,703000};

__constant__ int g_nGrp[4]    = {1,3,1,1};
__constant__ int g_Loff[4][3] = {{1600000,0,0},{0,3216000,4848000},{3200000,0,0},{4816000,0,0}};
__constant__ int g_ai[4][3]   = {{1,0,0},{0,2,3},{1,0,0},{1,0,0}};

// k4 fused-launch block ranges: U 782, P 782, C 8, B 16
#define K4_BU 782
#define K4_BP 1564
#define K4_BC 1572
#define K4_BT 1588

struct Ptrs {
    const float* x[4];
    const int*   ei[10];
    const int*   attr[4];   // for edge types 6..9
};

__device__ __forceinline__ void decode_et(int eflat, int& et, int& le) {
    if (eflat < 600000) { et = eflat / 100000; le = eflat - et * 100000; }
    else { int r = eflat - 600000; int q = r / 50000; et = 6 + q; le = r - q * 50000; }
}

// sum across the 16-lane quarter-wave group
__device__ __forceinline__ float qsum(float v) {
    v += __shfl_xor(v, 1, 64);
    v += __shfl_xor(v, 2, 64);
    v += __shfl_xor(v, 4, 64);
    v += __shfl_xor(v, 8, 64);
    return v;
}

// ---------------- K0: w0 tables + bs ----------------
__global__ void k0_tables(const float* __restrict__ Wb, const float* __restrict__ A,
                          const float* __restrict__ B, const float* __restrict__ behW,
                          const float* __restrict__ a_att,
                          float* __restrict__ w0, float* __restrict__ bs_out)
{
    __shared__ float a0[128];
    __shared__ float c0[128];
    __shared__ float g0[4][16];
    int t = threadIdx.x;
    if (t < 128) a0[t] = a_att[t];
    __syncthreads();
    if (t < 128) {
        float s0=0.f;
        for (int j=0;j<128;j++) s0 += Wb[j*128+t]*a0[j];
        c0[t]=s0;
    } else if (t < 192) {
        int q=t-128, p=q>>4, r=q&15;
        float s0=0.f;
        for (int i=0;i<128;i++) s0 += A[p*2048+i*16+r]*a0[i];
        g0[p][r]=s0;
    } else if (t < 196) {
        int b=t-192; float s=0.f;
        for (int i=0;i<128;i++) s += behW[b*128+i]*a_att[384+i];
        bs_out[b]=s;
    }
    __syncthreads();
    if (t < 128) {
        for (int et=0; et<10; ++et) {
            int phi=c_phi[et], beta=c_beta[et];
            if (beta >= 0) {
                float s0=c0[t];
                for (int r=0;r<16;r++) s0 += B[beta*2048+t*16+r]*g0[phi][r];
                w0[et*384+t]=s0; w0[et*384+128+t]=s0; w0[et*384+256+t]=s0;
            } else {
                for (int o=0;o<3;o++){
                    float s0=c0[t];
                    for (int r=0;r<16;r++) s0 += B[o*2048+t*16+r]*g0[phi][r];
                    w0[et*384+o*128+t]=s0;
                }
            }
        }
    }
}

// ---------------- ktrans: W_base^T and A^T precompute ----------------
__global__ __launch_bounds__(256) void ktrans(const float* __restrict__ Wb,
        const float* __restrict__ A, float* __restrict__ WbT, float* __restrict__ AT)
{
    int idx = blockIdx.x*256 + threadIdx.x;
    if (idx < 16384) { int i = idx>>7, j = idx&127; WbT[i*128+j] = Wb[j*128+i]; }
    int idx2 = idx - 16384;
    if (idx2 >= 0 && idx2 < 8192) {
        int p = idx2>>11, rem = idx2&2047, r = rem>>7, j = rem&127;
        AT[idx2] = A[p*2048 + j*16 + r];
    }
}

// ---------------- CSR build ----------------
__global__ __launch_bounds__(256) void khist(Ptrs P, int* __restrict__ counts)
{
    int eflat = blockIdx.x*256 + threadIdx.x;
    if (eflat >= ETOT) return;
    int et, le; decode_et(eflat, et, le);
    int dst = P.ei[et][c_E[et] + le];
    atomicAdd(&counts[c_moff[et] + dst], 1);
}

__global__ __launch_bounds__(256) void kscan1(const int* __restrict__ cnt,
                                              int* __restrict__ st, int* __restrict__ bsums)
{
    __shared__ int lds[256];
    int t = threadIdx.x, b = blockIdx.x;
    int base = b*1024 + t*4;
    int v0 = (base   < NSEG) ? cnt[base]   : 0;
    int v1 = (base+1 < NSEG) ? cnt[base+1] : 0;
    int v2 = (base+2 < NSEG) ? cnt[base+2] : 0;
    int v3 = (base+3 < NSEG) ? cnt[base+3] : 0;
    int s = v0+v1+v2+v3;
    lds[t] = s; __syncthreads();
    for (int off=1; off<256; off<<=1){
        int xv = (t>=off) ? lds[t-off] : 0;
        __syncthreads();
        lds[t] += xv;
        __syncthreads();
    }
    int incl = lds[t];
    int p = incl - s;
    if (t==255) bsums[b] = incl;
    if (base   < NSEG) st[base]   = p; p += v0;
    if (base+1 < NSEG) st[base+1] = p; p += v1;
    if (base+2 < NSEG) st[base+2] = p; p += v2;
    if (base+3 < NSEG) st[base+3] = p;
}

__global__ __launch_bounds__(256) void kscan2(int* __restrict__ bsums)
{
    __shared__ int lds[256];
    int t = threadIdx.x;
    int base = t*4;
    int v0 = (base   < NBLK) ? bsums[base]   : 0;
    int v1 = (base+1 < NBLK) ? bsums[base+1] : 0;
    int v2 = (base+2 < NBLK) ? bsums[base+2] : 0;
    int v3 = (base+3 < NBLK) ? bsums[base+3] : 0;
    int s = v0+v1+v2+v3;
    lds[t] = s; __syncthreads();
    for (int off=1; off<256; off<<=1){
        int xv = (t>=off) ? lds[t-off] : 0;
        __syncthreads();
        lds[t] += xv;
        __syncthreads();
    }
    int p = lds[t] - s;
    if (base   < NBLK) bsums[base]   = p; p += v0;
    if (base+1 < NBLK) bsums[base+1] = p; p += v1;
    if (base+2 < NBLK) bsums[base+2] = p; p += v2;
    if (base+3 < NBLK) bsums[base+3] = p;
}

__global__ __launch_bounds__(256) void kscan3(int* __restrict__ st, const int* __restrict__ bsums)
{
    int t = threadIdx.x, b = blockIdx.x;
    int add = bsums[b];
    int base = b*1024 + t*4;
    #pragma unroll
    for (int j=0;j<4;j++)
        if (base+j < NSEG) st[base+j] += add;
}

__global__ __launch_bounds__(256) void kscatter(Ptrs P, int* __restrict__ st, int* __restrict__ srco)
{
    int eflat = blockIdx.x*256 + threadIdx.x;
    if (eflat >= ETOT) return;
    int et, le; decode_et(eflat, et, le);
    const int* ei = P.ei[et];
    int E = c_E[et];
    int src = ei[le], dst = ei[E+le];
    int o;
    if (et >= 6) { int a = P.attr[et-6][le]; o = min(max(a,0),2); }
    else o = c_beta[et];
    int pos = atomicAdd(&st[c_moff[et] + dst], 1);
    srco[pos] = src | (o<<17) | (et<<19);
}
// after kscatter: st[seg] == segment end; start = st[seg] - counts[seg]

// ---------------- str_seg: one structural segment (3-bucket origin softmax) ----------
__device__ __forceinline__ void str_seg(int cnt, int st0, int hv,
        const int* __restrict__ srco, const float* __restrict__ xs,
        const float* __restrict__ wbase, float bs0, float bs1, float bs2,
        const float* __restrict__ Bm, int grp, int ln,
        float Stot[8], float* __restrict__ Lrow)
{
    if (cnt == 0) return;
    float ssum = 0.f;
    float SA[8]={0,0,0,0,0,0,0,0}, SB[8]={0,0,0,0,0,0,0,0}, SC[8]={0,0,0,0,0,0,0,0};
    int fa=0, fb=0, fc=0;

    for (int k0=0; k0<cnt; k0+=4) {
        bool act = (k0+grp) < cnt;
        int sv = (k0 == 0) ? hv : (act ? srco[st0+k0+grp] : 0);
        int o = (sv>>17)&3;
        float4 hA = make_float4(0.f,0.f,0.f,0.f), hB = hA;
        if (act) {
            const float* q = xs + (size_t)(sv & 0x1FFFF)*D + ln*8;
            hA = *(const float4*)q; hB = *(const float4*)(q+4);
        }
        const float* wq = wbase + o*128 + ln*8;
        float4 wA = *(const float4*)wq, wB = *(const float4*)(wq+4);
        float d = hA.x*wA.x + hA.y*wA.y + hA.z*wA.z + hA.w*wA.w
                + hB.x*wB.x + hB.y*wB.y + hB.z*wB.z + hB.w*wB.w;
        d = qsum(d);
        float wg = act ? __expf(d + ((o==0)?bs0:((o==1)?bs1:bs2))) : 0.f;
        ssum += wg;
        fa |= (int)(act && (o==0)); fb |= (int)(act && (o==1)); fc |= (int)(act && (o==2));
        float wg0=(o==0)?wg:0.f, wg1=(o==1)?wg:0.f, wg2=(o==2)?wg:0.f;
        #pragma unroll
        for (int j=0;j<8;j++){
            float hj = (j==0)?hA.x:(j==1)?hA.y:(j==2)?hA.z:(j==3)?hA.w:
                       (j==4)?hB.x:(j==5)?hB.y:(j==6)?hB.z:hB.w;
            SA[j] += wg0*hj; SB[j] += wg1*hj; SC[j] += wg2*hj;
        }
    }

    ssum += __shfl_xor(ssum, 16, 64);
    ssum += __shfl_xor(ssum, 32, 64);
    float inv = 1.f/(ssum + 1e-16f);

    int anyA = __any(fa), anyB = __any(fb), anyC = __any(fc);
    if (anyA) {
        #pragma unroll
        for (int j=0;j<8;j++){ SA[j] += __shfl_xor(SA[j],16,64); SA[j] += __shfl_xor(SA[j],32,64); }
    }
    if (anyB) {
        #pragma unroll
        for (int j=0;j<8;j++){ SB[j] += __shfl_xor(SB[j],16,64); SB[j] += __shfl_xor(SB[j],32,64); }
    }
    if (anyC) {
        #pragma unroll
        for (int j=0;j<8;j++){ SC[j] += __shfl_xor(SC[j],16,64); SC[j] += __shfl_xor(SC[j],32,64); }
    }
    #pragma unroll
    for (int j=0;j<8;j++) Stot[j] += (SA[j]+SB[j]+SC[j])*inv;

    float p0=0.f,p1=0.f,p2=0.f,p3=0.f;
    if (anyA) {
        const float* Bp = Bm + grp*4;
        #pragma unroll
        for (int j=0;j<8;j++){
            float4 b4 = *(const float4*)(Bp + (ln*8+j)*16);
            float v = SA[j];
            p0+=v*b4.x; p1+=v*b4.y; p2+=v*b4.z; p3+=v*b4.w;
        }
    }
    if (anyB) {
        const float* Bp = Bm + 2048 + grp*4;
        #pragma unroll
        for (int j=0;j<8;j++){
            float4 b4 = *(const float4*)(Bp + (ln*8+j)*16);
            float v = SB[j];
            p0+=v*b4.x; p1+=v*b4.y; p2+=v*b4.z; p3+=v*b4.w;
        }
    }
    if (anyC) {
        const float* Bp = Bm + 4096 + grp*4;
        #pragma unroll
        for (int j=0;j<8;j++){
            float4 b4 = *(const float4*)(Bp + (ln*8+j)*16);
            float v = SC[j];
            p0+=v*b4.x; p1+=v*b4.y; p2+=v*b4.z; p3+=v*b4.w;
        }
    }
    p0 = qsum(p0)*inv; p1 = qsum(p1)*inv; p2 = qsum(p2)*inv; p3 = qsum(p3)*inv;
    if (ln < 4) {
        float v = (ln==0)?p0:((ln==1)?p1:((ln==2)?p2:p3));
        Lrow[grp*4 + ln] = v;
    }
}

// ---------------- kagg_all: merged behavioral + structural, one dispatch --------------
// id < 200000: behavioral node (R9 path). 200000..299999: product structural (S -> S2).
// 300000..300999: category. 301000..302999: brand.
__global__ __launch_bounds__(256) void kagg_all(Ptrs P,
        const int* __restrict__ starts, const int* __restrict__ counts,
        const int* __restrict__ srco,
        const float* __restrict__ w0, const float* __restrict__ bs,
        const float* __restrict__ Bm,
        float* __restrict__ Sout, float* __restrict__ S2,
        float* __restrict__ Lb, int nWaves)
{
    int lane = threadIdx.x & 63;
    int wv = (blockIdx.x * 256 + threadIdx.x) >> 6;
    int grp = lane >> 4, ln = lane & 15;
    float bs0 = bs[0], bs1 = bs[1], bs2 = bs[2];

    for (int id = wv; id < NID_ALL; id += nWaves) {
        if (id < 200000) {
            // ---- behavioral node (R9 structure, fp32) ----
            int T = (id < NU) ? 0 : 1;
            int n0 = (T == 0) ? id : id - NU;
            int etBase = (T == 0) ? 3 : 0;
            const float* xs = P.x[1 - T];

            int sgA = c_moff[etBase] + n0;
            int cnt0 = counts[sgA],        cnt1 = counts[sgA+100000], cnt2 = counts[sgA+200000];
            int sa0  = starts[sgA]-cnt0,   sa1  = starts[sgA+100000]-cnt1, sa2 = starts[sgA+200000]-cnt2;
            int sv1 = (grp < cnt1) ? srco[sa1+grp] : 0;
            int sv2 = (grp < cnt2) ? srco[sa2+grp] : 0;
            float4 pA = make_float4(0.f,0.f,0.f,0.f), pB = pA;
            if (grp < cnt0) {
                int sv0 = srco[sa0+grp];
                const float* q = xs + (size_t)(sv0 & 0x1FFFF)*D + ln*8;
                pA = *(const float4*)q; pB = *(const float4*)(q+4);
            }

            float Stot[8] = {0,0,0,0,0,0,0,0};
            float Lq0=0.f, Lq1=0.f, Lq2=0.f, Lq3=0.f;

            for (int s=0; s<3; ++s) {
                int cnt = (s==0)?cnt0:((s==1)?cnt1:cnt2);
                int st0 = (s==0)?sa0:((s==1)?sa1:sa2);
                float4 cA = pA, cB = pB;
                pA = make_float4(0.f,0.f,0.f,0.f); pB = pA;
                if (s == 0) {
                    if (grp < cnt1) {
                        const float* q = xs + (size_t)(sv1 & 0x1FFFF)*D + ln*8;
                        pA = *(const float4*)q; pB = *(const float4*)(q+4);
                    }
                } else if (s == 1) {
                    if (grp < cnt2) {
                        const float* q = xs + (size_t)(sv2 & 0x1FFFF)*D + ln*8;
                        pA = *(const float4*)q; pB = *(const float4*)(q+4);
                    }
                }
                if (cnt == 0) continue;
                int et = etBase + s;
                const float* wq = w0 + et*384 + ln*8;
                float4 wA = *(const float4*)wq, wB = *(const float4*)(wq+4);

                float ssum = 0.f;
                float SA[8] = {0,0,0,0,0,0,0,0};

                for (int k0=0; k0<cnt; k0+=4) {
                    bool act = (k0+grp) < cnt;
                    if (k0 > 0) {
                        cA = make_float4(0.f,0.f,0.f,0.f); cB = cA;
                        if (act) {
                            int sv = srco[st0+k0+grp];
                            const float* q = xs + (size_t)(sv & 0x1FFFF)*D + ln*8;
                            cA = *(const float4*)q; cB = *(const float4*)(q+4);
                        }
                    }
                    float d = cA.x*wA.x + cA.y*wA.y + cA.z*wA.z + cA.w*wA.w
                            + cB.x*wB.x + cB.y*wB.y + cB.z*wB.z + cB.w*wB.w;
                    d = qsum(d);
                    float wg = act ? __expf(d) : 0.f;   // no-max softmax (shift-invariant)
                    ssum += wg;
                    SA[0]+=wg*cA.x; SA[1]+=wg*cA.y; SA[2]+=wg*cA.z; SA[3]+=wg*cA.w;
                    SA[4]+=wg*cB.x; SA[5]+=wg*cB.y; SA[6]+=wg*cB.z; SA[7]+=wg*cB.w;
                }
                ssum += __shfl_xor(ssum, 16, 64);
                ssum += __shfl_xor(ssum, 32, 64);
                float inv = 1.f/(ssum + 1e-16f);
                #pragma unroll
                for (int j=0;j<8;j++){ SA[j] += __shfl_xor(SA[j],16,64); SA[j] += __shfl_xor(SA[j],32,64); }
                #pragma unroll
                for (int j=0;j<8;j++) Stot[j] += SA[j]*inv;

                const float* Bp = Bm + s*2048 + grp*4;
                float p0=0.f,p1=0.f,p2=0.f,p3=0.f;
                #pragma unroll
                for (int j=0;j<8;j++){
                    float4 b4 = *(const float4*)(Bp + (ln*8+j)*16);
                    float v = SA[j];
                    p0+=v*b4.x; p1+=v*b4.y; p2+=v*b4.z; p3+=v*b4.w;
                }
                Lq0 += qsum(p0)*inv; Lq1 += qsum(p1)*inv;
                Lq2 += qsum(p2)*inv; Lq3 += qsum(p3)*inv;
            }

            if (grp == 0) {
                float* Srow = Sout + (size_t)id*D + ln*8;
                *(float4*)Srow     = make_float4(Stot[0],Stot[1],Stot[2],Stot[3]);
                *(float4*)(Srow+4) = make_float4(Stot[4],Stot[5],Stot[6],Stot[7]);
            }
            if (ln < 4) {
                float v = (ln==0)?Lq0:((ln==1)?Lq1:((ln==2)?Lq2:Lq3));
                int loff = (T==0) ? 1600000 : 0;
                Lb[loff + (size_t)n0*16 + grp*4 + ln] = v;
            }
        } else if (id < 300000) {
            // ---- product structural: skip-empty; store into S2 (pre-zeroed) ----
            int n0 = id - 200000;
            int seg7 = 601000 + n0, seg9 = 703000 + n0;
            int cnt7 = counts[seg7], cnt9 = counts[seg9];
            if ((cnt7 | cnt9) == 0) continue;
            int st7 = starts[seg7] - cnt7, st9 = starts[seg9] - cnt9;
            int hv7 = (grp < cnt7) ? srco[st7+grp] : 0;
            int hv9 = (grp < cnt9) ? srco[st9+grp] : 0;

            float Stot[8] = {0,0,0,0,0,0,0,0};
            str_seg(cnt7, st7, hv7, srco, P.x[2], w0 + 7*384,
                    bs0, bs1, bs2, Bm, grp, ln, Stot,
                    Lb + 3216000 + (size_t)n0*16);
            str_seg(cnt9, st9, hv9, srco, P.x[3], w0 + 9*384,
                    bs0, bs1, bs2, Bm, grp, ln, Stot,
                    Lb + 4848000 + (size_t)n0*16);

            if (grp == 0) {
                float* Srow = S2 + (size_t)n0*D + ln*8;
                *(float4*)Srow     = make_float4(Stot[0],Stot[1],Stot[2],Stot[3]);
                *(float4*)(Srow+4) = make_float4(Stot[4],Stot[5],Stot[6],Stot[7]);
            }
        } else {
            // ---- category / brand ----
            int T = (id < 301000) ? 2 : 3;
            int n0 = (T==2) ? (id-300000) : (id-301000);
            int et = (T==2) ? 6 : 8;
            int outRow = (T==2) ? (200000+n0) : (201000+n0);
            int seg = c_moff[et] + n0;
            int cnt = counts[seg];
            int st0 = starts[seg] - cnt;
            int hv  = (grp < cnt) ? srco[st0+grp] : 0;

            float Stot[8] = {0,0,0,0,0,0,0,0};
            int loff = (T==2) ? 3200000 : 4816000;
            str_seg(cnt, st0, hv, srco, P.x[1], w0 + et*384,
                    bs0, bs1, bs2, Bm, grp, ln, Stot,
                    Lb + loff + (size_t)n0*16);
            if (cnt == 0 && ln < 4) Lb[loff + (size_t)n0*16 + grp*4 + ln] = 0.f;

            if (grp == 0) {
                float* Srow = Sout + (size_t)outRow*D + ln*8;
                *(float4*)Srow     = make_float4(Stot[0],Stot[1],Stot[2],Stot[3]);
                *(float4*)(Srow+4) = make_float4(Stot[4],Stot[5],Stot[6],Stot[7]);
            }
        }
    }
}

// ---------------- K4 (fused): agg = W_base@S(+S2) + sum A[p]@L_p, LN+ELU+residual ----
__global__ __launch_bounds__(512, 1) void k4_final(Ptrs P,
        const float* __restrict__ WbT, const float* __restrict__ AT,
        const float* __restrict__ Lb, const float* __restrict__ S2,
        const float* __restrict__ gamma, const float* __restrict__ lbeta,
        float* __restrict__ out)
{
    __shared__ float st[128*132];   // S tile, stride 132
    __shared__ float wt[128*128];   // WbT tile: wt[i*128 + j]
    __shared__ float lt[128*52];    // L tile: lt[r*52 + pi*16 + k]
    int t = threadIdx.x;
    int b = blockIdx.x;
    int T, lb;
    if (b < K4_BU)      { T=0; lb=b; }
    else if (b < K4_BP) { T=1; lb=b-K4_BU; }
    else if (b < K4_BC) { T=2; lb=b-K4_BP; }
    else                { T=3; lb=b-K4_BC; }
    int r0 = lb*128;
    int rowStart = (T==0)?0:((T==1)?100000:((T==2)?200000:201000));
    int nRows    = (T==0)?NU:((T==1)?NP:((T==2)?NC:NB));
    const float* x = P.x[T];
    int nPairs = g_nGrp[T];

    for (int idx=t; idx<4096; idx+=512)
        *(float4*)&wt[idx*4] = *(const float4*)&WbT[idx*4];
    for (int idx=t; idx<4096; idx+=512){
        int r = idx>>5, i4 = idx&31;
        int lr = r0 + r;
        float4 v = make_float4(0.f,0.f,0.f,0.f);
        if (lr < nRows) {
            v = *(const float4*)&out[(size_t)(rowStart+lr)*D + i4*4];
            if (T == 1) {
                float4 w2 = *(const float4*)&S2[(size_t)lr*D + i4*4];
                v.x += w2.x; v.y += w2.y; v.z += w2.z; v.w += w2.w;
            }
        }
        *(float4*)&st[r*132 + i4*4] = v;
    }
    for (int pi=0; pi<nPairs; ++pi){
        int lo = g_Loff[T][pi];
        int r = t>>2, q = t&3;
        int lr = r0 + r;
        float4 v = (lr < nRows) ? *(const float4*)&Lb[lo + (size_t)lr*16 + q*4]
                                : make_float4(0.f,0.f,0.f,0.f);
        *(float4*)&lt[r*52 + pi*16 + q*4] = v;
    }
    __syncthreads();

    int cg = t & 15, rg = t >> 4;
    float acc[4][8];
    #pragma unroll
    for (int a=0;a<4;a++)
        #pragma unroll
        for (int c=0;c<8;c++) acc[a][c]=0.f;

    for (int i4=0; i4<32; ++i4){
        float4 sv0 = *(const float4*)&st[(rg*4+0)*132 + i4*4];
        float4 sv1 = *(const float4*)&st[(rg*4+1)*132 + i4*4];
        float4 sv2 = *(const float4*)&st[(rg*4+2)*132 + i4*4];
        float4 sv3 = *(const float4*)&st[(rg*4+3)*132 + i4*4];
        #pragma unroll
        for (int q=0;q<4;q++){
            float4 wA = *(const float4*)&wt[(i4*4+q)*128 + cg*4];
            float4 wB = *(const float4*)&wt[(i4*4+q)*128 + 64 + cg*4];
            float sq[4];
            sq[0] = (q==0)?sv0.x:(q==1)?sv0.y:(q==2)?sv0.z:sv0.w;
            sq[1] = (q==0)?sv1.x:(q==1)?sv1.y:(q==2)?sv1.z:sv1.w;
            sq[2] = (q==0)?sv2.x:(q==1)?sv2.y:(q==2)?sv2.z:sv2.w;
            sq[3] = (q==0)?sv3.x:(q==1)?sv3.y:(q==2)?sv3.z:sv3.w;
            #pragma unroll
            for (int rr=0;rr<4;rr++){
                acc[rr][0] += sq[rr]*wA.x;
                acc[rr][1] += sq[rr]*wA.y;
                acc[rr][2] += sq[rr]*wA.z;
                acc[rr][3] += sq[rr]*wA.w;
                acc[rr][4] += sq[rr]*wB.x;
                acc[rr][5] += sq[rr]*wB.y;
                acc[rr][6] += sq[rr]*wB.z;
                acc[rr][7] += sq[rr]*wB.w;
            }
        }
    }

    for (int pi=0; pi<nPairs; ++pi){
        int ai = g_ai[T][pi];
        const float* Ap = AT + ai*2048;
        #pragma unroll 4
        for (int r=0;r<16;++r){
            float4 aA = *(const float4*)&Ap[r*128 + cg*4];
            float4 aB = *(const float4*)&Ap[r*128 + 64 + cg*4];
            float lv[4];
            #pragma unroll
            for (int rr=0;rr<4;rr++) lv[rr] = lt[(rg*4+rr)*52 + pi*16 + r];
            #pragma unroll
            for (int rr=0;rr<4;rr++){
                acc[rr][0] += lv[rr]*aA.x;
                acc[rr][1] += lv[rr]*aA.y;
                acc[rr][2] += lv[rr]*aA.z;
                acc[rr][3] += lv[rr]*aA.w;
                acc[rr][4] += lv[rr]*aB.x;
                acc[rr][5] += lv[rr]*aB.y;
                acc[rr][6] += lv[rr]*aB.z;
                acc[rr][7] += lv[rr]*aB.w;
            }
        }
    }

    int jA = cg*4, jB = 64 + cg*4;
    float4 gA = *(const float4*)&gamma[jA], gB = *(const float4*)&gamma[jB];
    float4 bA = *(const float4*)&lbeta[jA], bB = *(const float4*)&lbeta[jB];
    float gv[8] = {gA.x,gA.y,gA.z,gA.w,gB.x,gB.y,gB.z,gB.w};
    float bv[8] = {bA.x,bA.y,bA.z,bA.w,bB.x,bB.y,bB.z,bB.w};

    #pragma unroll
    for (int rr=0;rr<4;rr++){
        int lr = r0 + rg*4 + rr;
        float lsum=0.f, lsq=0.f;
        #pragma unroll
        for (int c=0;c<8;c++){ lsum += acc[rr][c]; lsq += acc[rr][c]*acc[rr][c]; }
        #pragma unroll
        for (int mm=1; mm<16; mm<<=1){ lsum += __shfl_xor(lsum,mm,64); lsq += __shfl_xor(lsq,mm,64); }
        if (lr >= nRows) continue;
        float mu = lsum*(1.f/128.f);
        float var = lsq*(1.f/128.f) - mu*mu;
        float rstd = rsqrtf(var + 1e-5f);
        const float* xr = x + (size_t)lr*D;
        float4 xA = *(const float4*)(xr+jA), xB = *(const float4*)(xr+jB);
        float xv[8] = {xA.x,xA.y,xA.z,xA.w,xB.x,xB.y,xB.z,xB.w};
        float ov[8];
        #pragma unroll
        for (int c=0;c<8;c++){
            float hn = (acc[rr][c]-mu)*rstd*gv[c] + bv[c];
            float z = hn + xv[c];
            ov[c] = z > 0.f ? z : expm1f(z);
        }
        float* orow = out + (size_t)(rowStart+lr)*D;
        *(float4*)(orow+jA) = make_float4(ov[0],ov[1],ov[2],ov[3]);
        *(float4*)(orow+jB) = make_float4(ov[4],ov[5],ov[6],ov[7]);
    }
}

extern "C" void kernel_launch(void* const* d_in, const int* in_sizes, int n_in,
                              void* d_out, int out_size, void* d_ws, size_t ws_size,
                              hipStream_t stream)
{
    (void)in_sizes; (void)n_in; (void)out_size; (void)ws_size;
    Ptrs P;
    P.x[0] = (const float*)d_in[0];   // x_user
    P.x[1] = (const float*)d_in[1];   // x_product
    P.x[2] = (const float*)d_in[2];   // x_category
    P.x[3] = (const float*)d_in[3];   // x_brand
    P.ei[0] = (const int*)d_in[4];    // view
    P.ei[1] = (const int*)d_in[5];    // cart
    P.ei[2] = (const int*)d_in[6];    // purchase
    P.ei[3] = (const int*)d_in[7];    // rev_view
    P.ei[4] = (const int*)d_in[8];    // rev_cart
    P.ei[5] = (const int*)d_in[9];    // rev_purchase
    P.ei[6] = (const int*)d_in[10];   // belongs_to
    P.attr[0] = (const int*)d_in[11];
    P.ei[7] = (const int*)d_in[12];   // contains
    P.attr[1] = (const int*)d_in[13];
    P.ei[8] = (const int*)d_in[14];   // producedBy
    P.attr[2] = (const int*)d_in[15];
    P.ei[9] = (const int*)d_in[16];   // brands
    P.attr[3] = (const int*)d_in[17];
    const float* Wb    = (const float*)d_in[18];
    const float* A     = (const float*)d_in[19];
    const float* B     = (const float*)d_in[20];
    const float* behW  = (const float*)d_in[22];
    const float* a_att = (const float*)d_in[23];
    const float* gamma = (const float*)d_in[24];
    const float* lbeta = (const float*)d_in[25];
    float* wsf = (float*)d_ws;
    float* out = (float*)d_out;

    int* ip     = (int*)(wsf + OFF_INT);
    int* counts = ip;
    int* starts = ip + 803000;
    int* srco   = ip + 1606000;
    int* bsums  = (int*)wsf;          // overlays product L-group0 (fully rewritten by beh path)
    float* S2   = wsf + OFF_S2;

    hipMemsetAsync(counts, 0, (size_t)NSEG*sizeof(int), stream);
    // zero L regions that may be skipped (product structural groups)
    hipMemsetAsync(wsf + 3216000, 0, (size_t)(6448000-3216000)*sizeof(float), stream);
    // zero S2 (product structural S contributions; skipped products stay zero)
    hipMemsetAsync(S2, 0, (size_t)12800000*sizeof(float), stream);

    k0_tables<<<1, 256, 0, stream>>>(Wb, A, B, behW, a_att, wsf+OFF_W0, wsf+OFF_BS);
    ktrans<<<96, 256, 0, stream>>>(Wb, A, wsf+OFF_WT, wsf+OFF_AT);
    khist<<<3125, 256, 0, stream>>>(P, counts);
    kscan1<<<NBLK, 256, 0, stream>>>(counts, starts, bsums);
    kscan2<<<1, 256, 0, stream>>>(bsums);
    kscan3<<<NBLK, 256, 0, stream>>>(starts, bsums);
    kscatter<<<3125, 256, 0, stream>>>(P, starts, srco);

    kagg_all<<<4096, 256, 0, stream>>>(P, starts, counts, srco,
                                       wsf+OFF_W0, wsf+OFF_BS, B,
                                       out, S2, wsf+OFF_L, 4096*4);

    k4_final<<<K4_BT, 512, 0, stream>>>(P, wsf+OFF_WT, wsf+OFF_AT, wsf+OFF_L, S2,
                                        gamma, lbeta, out);
}

// Round 15
// 859.948 us; speedup vs baseline: 1.0601x; 1.0321x over previous
//
#include <hip/hip_runtime.h>
#include <hip/hip_bf16.h>
#include <math.h>

#define D 128

// problem sizes (fixed by reference)
#define NU 100000
#define NP 100000
#define NC 1000
#define NB 2000
#define NTOT 203000
#define EB 100000
#define ES 50000
#define ETOT 800000
#define NSEG 803000
#define NBLK 785          // ceil(NSEG/1024)
#define NTOTB 200000      // behavioral dst nodes (user+product)

// ws layout (float offsets)
#define OFF_L    0            // 6448000 floats: low-rank accumulators
#define OFF_W0   6448000      // 10*3*128
#define OFF_BS   6451840      // 16 (bs[4])
#define OFF_WT   7251856      // 16384 floats: W_base^T
#define OFF_AT   7268240      // 8192 floats: A^T per phi
#define OFF_INT  7276432      // int region
// ints relative to (int*)(wsf+OFF_INT):
//   counts @ 0        (803000)
//   starts @ 803000   (803000)  -- after kscatter: segment END
//   srco   @ 1606000  (800000)  -- src | o<<17 | et<<19, CSR order (o = beta for behavioral)

// per-edge-type metadata
__constant__ int c_srcT[10]   = {0,0,0,1,1,1,1,2,1,3};
__constant__ int c_phi [10]   = {0,0,0,1,1,1,1,2,1,3};
__constant__ int c_beta[10]   = {0,1,2,0,1,2,-1,-1,-1,-1};
__constant__ int c_E   [10]   = {EB,EB,EB,EB,EB,EB,ES,ES,ES,ES};
__constant__ int c_moff[10]   = {0,100000,200000,300000,400000,500000,600000,601000,701000,703000};

__constant__ int g_nGrp[4]    = {1,3,1,1};
__constant__ int g_Loff[4][3] = {{1600000,0,0},{0,3216000,4848000},{3200000,0,0},{4816000,0,0}};
__constant__ int g_ai[4][3]   = {{1,0,0},{0,2,3},{1,0,0},{1,0,0}};

// k4 fused-launch block ranges: U 782, P 782, C 8, B 16
#define K4_BU 782
#define K4_BP 1564
#define K4_BC 1572
#define K4_BT 1588

struct Ptrs {
    const float* x[4];
    const int*   ei[10];
    const int*   attr[4];   // for edge types 6..9
};

__device__ __forceinline__ void decode_et(int eflat, int& et, int& le) {
    if (eflat < 600000) { et = eflat / 100000; le = eflat - et * 100000; }
    else { int r = eflat - 600000; int q = r / 50000; et = 6 + q; le = r - q * 50000; }
}

// sum across the 16-lane quarter-wave group
__device__ __forceinline__ float qsum(float v) {
    v += __shfl_xor(v, 1, 64);
    v += __shfl_xor(v, 2, 64);
    v += __shfl_xor(v, 4, 64);
    v += __shfl_xor(v, 8, 64);
    return v;
}

// ---------------- K0: w0 tables + bs ----------------
__global__ void k0_tables(const float* __restrict__ Wb, const float* __restrict__ A,
                          const float* __restrict__ B, const float* __restrict__ behW,
                          const float* __restrict__ a_att,
                          float* __restrict__ w0, float* __restrict__ bs_out)
{
    __shared__ float a0[128];
    __shared__ float c0[128];
    __shared__ float g0[4][16];
    int t = threadIdx.x;
    if (t < 128) a0[t] = a_att[t];
    __syncthreads();
    if (t < 128) {
        float s0=0.f;
        for (int j=0;j<128;j++) s0 += Wb[j*128+t]*a0[j];
        c0[t]=s0;
    } else if (t < 192) {
        int q=t-128, p=q>>4, r=q&15;
        float s0=0.f;
        for (int i=0;i<128;i++) s0 += A[p*2048+i*16+r]*a0[i];
        g0[p][r]=s0;
    } else if (t < 196) {
        int b=t-192; float s=0.f;
        for (int i=0;i<128;i++) s += behW[b*128+i]*a_att[384+i];
        bs_out[b]=s;
    }
    __syncthreads();
    if (t < 128) {
        for (int et=0; et<10; ++et) {
            int phi=c_phi[et], beta=c_beta[et];
            if (beta >= 0) {
                float s0=c0[t];
                for (int r=0;r<16;r++) s0 += B[beta*2048+t*16+r]*g0[phi][r];
                w0[et*384+t]=s0; w0[et*384+128+t]=s0; w0[et*384+256+t]=s0;
            } else {
                for (int o=0;o<3;o++){
                    float s0=c0[t];
                    for (int r=0;r<16;r++) s0 += B[o*2048+t*16+r]*g0[phi][r];
                    w0[et*384+o*128+t]=s0;
                }
            }
        }
    }
}

// ---------------- ktrans: W_base^T and A^T precompute ----------------
__global__ __launch_bounds__(256) void ktrans(const float* __restrict__ Wb,
        const float* __restrict__ A, float* __restrict__ WbT, float* __restrict__ AT)
{
    int idx = blockIdx.x*256 + threadIdx.x;
    if (idx < 16384) { int i = idx>>7, j = idx&127; WbT[i*128+j] = Wb[j*128+i]; }
    int idx2 = idx - 16384;
    if (idx2 >= 0 && idx2 < 8192) {
        int p = idx2>>11, rem = idx2&2047, r = rem>>7, j = rem&127;
        AT[idx2] = A[p*2048 + j*16 + r];
    }
}

// ---------------- CSR build ----------------
__global__ __launch_bounds__(256) void khist(Ptrs P, int* __restrict__ counts)
{
    int eflat = blockIdx.x*256 + threadIdx.x;
    if (eflat >= ETOT) return;
    int et, le; decode_et(eflat, et, le);
    int dst = P.ei[et][c_E[et] + le];
    atomicAdd(&counts[c_moff[et] + dst], 1);
}

__global__ __launch_bounds__(256) void kscan1(const int* __restrict__ cnt,
                                              int* __restrict__ st, int* __restrict__ bsums)
{
    __shared__ int lds[256];
    int t = threadIdx.x, b = blockIdx.x;
    int base = b*1024 + t*4;
    int v0 = (base   < NSEG) ? cnt[base]   : 0;
    int v1 = (base+1 < NSEG) ? cnt[base+1] : 0;
    int v2 = (base+2 < NSEG) ? cnt[base+2] : 0;
    int v3 = (base+3 < NSEG) ? cnt[base+3] : 0;
    int s = v0+v1+v2+v3;
    lds[t] = s; __syncthreads();
    for (int off=1; off<256; off<<=1){
        int xv = (t>=off) ? lds[t-off] : 0;
        __syncthreads();
        lds[t] += xv;
        __syncthreads();
    }
    int incl = lds[t];
    int p = incl - s;
    if (t==255) bsums[b] = incl;
    if (base   < NSEG) st[base]   = p; p += v0;
    if (base+1 < NSEG) st[base+1] = p; p += v1;
    if (base+2 < NSEG) st[base+2] = p; p += v2;
    if (base+3 < NSEG) st[base+3] = p;
}

__global__ __launch_bounds__(256) void kscan2(int* __restrict__ bsums)
{
    __shared__ int lds[256];
    int t = threadIdx.x;
    int base = t*4;
    int v0 = (base   < NBLK) ? bsums[base]   : 0;
    int v1 = (base+1 < NBLK) ? bsums[base+1] : 0;
    int v2 = (base+2 < NBLK) ? bsums[base+2] : 0;
    int v3 = (base+3 < NBLK) ? bsums[base+3] : 0;
    int s = v0+v1+v2+v3;
    lds[t] = s; __syncthreads();
    for (int off=1; off<256; off<<=1){
        int xv = (t>=off) ? lds[t-off] : 0;
        __syncthreads();
        lds[t] += xv;
        __syncthreads();
    }
    int p = lds[t] - s;
    if (base   < NBLK) bsums[base]   = p; p += v0;
    if (base+1 < NBLK) bsums[base+1] = p; p += v1;
    if (base+2 < NBLK) bsums[base+2] = p; p += v2;
    if (base+3 < NBLK) bsums[base+3] = p;
}

__global__ __launch_bounds__(256) void kscan3(int* __restrict__ st, const int* __restrict__ bsums)
{
    int t = threadIdx.x, b = blockIdx.x;
    int add = bsums[b];
    int base = b*1024 + t*4;
    #pragma unroll
    for (int j=0;j<4;j++)
        if (base+j < NSEG) st[base+j] += add;
}

__global__ __launch_bounds__(256) void kscatter(Ptrs P, int* __restrict__ st, int* __restrict__ srco)
{
    int eflat = blockIdx.x*256 + threadIdx.x;
    if (eflat >= ETOT) return;
    int et, le; decode_et(eflat, et, le);
    const int* ei = P.ei[et];
    int E = c_E[et];
    int src = ei[le], dst = ei[E+le];
    int o;
    if (et >= 6) { int a = P.attr[et-6][le]; o = min(max(a,0),2); }
    else o = c_beta[et];
    int pos = atomicAdd(&st[c_moff[et] + dst], 1);
    srco[pos] = src | (o<<17) | (et<<19);
}
// after kscatter: st[seg] == segment end; start = st[seg] - counts[seg]

// ---------------- kagg_beh v5: R9 body + cross-node scalar pipeline -------------------
// Pipeline: seginfo issued 2 nodes ahead, srco-heads 1 node ahead -> only the x-gather
// round stays exposed per node.
__global__ __launch_bounds__(256) void kagg_beh(Ptrs P,
        const int* __restrict__ starts, const int* __restrict__ counts,
        const int* __restrict__ srco,
        const float* __restrict__ w0, const float* __restrict__ Bm,
        float* __restrict__ Sout, float* __restrict__ Lb, int nWaves)
{
    int lane = threadIdx.x & 63;
    int wv = (blockIdx.x * 256 + threadIdx.x) >> 6;
    int grp = lane >> 4, ln = lane & 15;

    if (wv >= NTOTB) return;

    // --- prologue: seginfo for node j (=wv), heads for j, seginfo for j+1 ---
    int a0,a1,a2,b0,b1,b2;          // cnt/end for current node j
    {
        int nid = wv;
        int sg = ((nid < NU) ? (300000 + nid) : (nid - NU));
        a0 = counts[sg];         a1 = counts[sg+100000];  a2 = counts[sg+200000];
        b0 = starts[sg];         b1 = starts[sg+100000];  b2 = starts[sg+200000];
    }
    int h0=0, h1=0, h2=0;           // srco heads for current node j
    if (grp < a0) h0 = srco[b0-a0+grp];
    if (grp < a1) h1 = srco[b1-a1+grp];
    if (grp < a2) h2 = srco[b2-a2+grp];
    int cc0=0,cc1=0,cc2=0, ce0=0,ce1=0,ce2=0;   // seginfo for node j+1
    if (wv + nWaves < NTOTB) {
        int nid = wv + nWaves;
        int sg = ((nid < NU) ? (300000 + nid) : (nid - NU));
        cc0 = counts[sg];        cc1 = counts[sg+100000]; cc2 = counts[sg+200000];
        ce0 = starts[sg];        ce1 = starts[sg+100000]; ce2 = starts[sg+200000];
    }

    for (int nid = wv; nid < NTOTB; nid += nWaves) {
        int T = (nid < NU) ? 0 : 1;
        int n0 = (T == 0) ? nid : nid - NU;
        int etBase = (T == 0) ? 3 : 0;
        const float* xs = P.x[1 - T];

        int cnt0 = a0, cnt1 = a1, cnt2 = a2;
        int sa0 = b0-a0, sa1 = b1-a1, sa2 = b2-a2;
        int sv1 = h1, sv2 = h2;

        // step 1: issue seginfo loads for node j+2 (consumed a full body later)
        int f0=0,f1=0,f2=0, g0=0,g1=0,g2=0;
        {
            int nid2 = nid + 2*nWaves;
            if (nid2 < NTOTB) {
                int sg = ((nid2 < NU) ? (300000 + nid2) : (nid2 - NU));
                f0 = counts[sg];     f1 = counts[sg+100000]; f2 = counts[sg+200000];
                g0 = starts[sg];     g1 = starts[sg+100000]; g2 = starts[sg+200000];
            }
        }

        // step 2: x head prefetch for segment 0 (h0 ready from last iteration)
        float4 pA = make_float4(0.f,0.f,0.f,0.f), pB = pA;
        if (grp < cnt0) {
            const float* q = xs + (size_t)(h0 & 0x1FFFF)*D + ln*8;
            pA = *(const float4*)q; pB = *(const float4*)(q+4);
        }

        // step 3: issue srco-head loads for node j+1 (its seginfo landed last iteration)
        int i0=0, i1=0, i2=0;
        if (nid + nWaves < NTOTB) {
            if (grp < cc0) i0 = srco[ce0-cc0+grp];
            if (grp < cc1) i1 = srco[ce1-cc1+grp];
            if (grp < cc2) i2 = srco[ce2-cc2+grp];
        }

        // step 4: body (R9 structure)
        float Stot[8] = {0,0,0,0,0,0,0,0};
        float Lq0=0.f, Lq1=0.f, Lq2=0.f, Lq3=0.f;

        for (int s=0; s<3; ++s) {
            int cnt = (s==0)?cnt0:((s==1)?cnt1:cnt2);
            int st0 = (s==0)?sa0:((s==1)?sa1:sa2);
            float4 cA = pA, cB = pB;
            // rolling prefetch: next segment's first-quad x
            pA = make_float4(0.f,0.f,0.f,0.f); pB = pA;
            if (s == 0) {
                if (grp < cnt1) {
                    const float* q = xs + (size_t)(sv1 & 0x1FFFF)*D + ln*8;
                    pA = *(const float4*)q; pB = *(const float4*)(q+4);
                }
            } else if (s == 1) {
                if (grp < cnt2) {
                    const float* q = xs + (size_t)(sv2 & 0x1FFFF)*D + ln*8;
                    pA = *(const float4*)q; pB = *(const float4*)(q+4);
                }
            }
            if (cnt == 0) continue;
            int et = etBase + s;
            const float* wq = w0 + et*384 + ln*8;
            float4 wA = *(const float4*)wq, wB = *(const float4*)(wq+4);

            float ssum = 0.f;
            float SA[8] = {0,0,0,0,0,0,0,0};

            for (int k0=0; k0<cnt; k0+=4) {
                bool act = (k0+grp) < cnt;
                if (k0 > 0) {
                    cA = make_float4(0.f,0.f,0.f,0.f); cB = cA;
                    if (act) {
                        int sv = srco[st0+k0+grp];
                        const float* q = xs + (size_t)(sv & 0x1FFFF)*D + ln*8;
                        cA = *(const float4*)q; cB = *(const float4*)(q+4);
                    }
                }
                float d = cA.x*wA.x + cA.y*wA.y + cA.z*wA.z + cA.w*wA.w
                        + cB.x*wB.x + cB.y*wB.y + cB.z*wB.z + cB.w*wB.w;
                d = qsum(d);
                float wg = act ? __expf(d) : 0.f;   // no-max softmax (shift-invariant)
                ssum += wg;
                SA[0]+=wg*cA.x; SA[1]+=wg*cA.y; SA[2]+=wg*cA.z; SA[3]+=wg*cA.w;
                SA[4]+=wg*cB.x; SA[5]+=wg*cB.y; SA[6]+=wg*cB.z; SA[7]+=wg*cB.w;
            }
            // cross-slot totals
            ssum += __shfl_xor(ssum, 16, 64);
            ssum += __shfl_xor(ssum, 32, 64);
            float inv = 1.f/(ssum + 1e-16f);
            #pragma unroll
            for (int j=0;j<8;j++){ SA[j] += __shfl_xor(SA[j],16,64); SA[j] += __shfl_xor(SA[j],32,64); }
            #pragma unroll
            for (int j=0;j<8;j++) Stot[j] += SA[j]*inv;

            // B[beta=s]^T SA : cols grp*4..+3, rows ln*8..+7
            const float* Bp = Bm + s*2048 + grp*4;
            float p0=0.f,p1=0.f,p2=0.f,p3=0.f;
            #pragma unroll
            for (int j=0;j<8;j++){
                float4 b4 = *(const float4*)(Bp + (ln*8+j)*16);
                float v = SA[j];
                p0+=v*b4.x; p1+=v*b4.y; p2+=v*b4.z; p3+=v*b4.w;
            }
            Lq0 += qsum(p0)*inv; Lq1 += qsum(p1)*inv;
            Lq2 += qsum(p2)*inv; Lq3 += qsum(p3)*inv;
        }

        // step 5: stores
        if (grp == 0) {
            float* Srow = Sout + (size_t)nid*D + ln*8;
            *(float4*)Srow     = make_float4(Stot[0],Stot[1],Stot[2],Stot[3]);
            *(float4*)(Srow+4) = make_float4(Stot[4],Stot[5],Stot[6],Stot[7]);
        }
        if (ln < 4) {
            float v = (ln==0)?Lq0:((ln==1)?Lq1:((ln==2)?Lq2:Lq3));
            int loff = (T==0) ? 1600000 : 0;
            Lb[loff + (size_t)n0*16 + grp*4 + ln] = v;
        }

        // step 6: rotate pipeline state
        a0 = cc0; a1 = cc1; a2 = cc2;
        b0 = ce0; b1 = ce1; b2 = ce2;
        cc0 = f0; cc1 = f1; cc2 = f2;
        ce0 = g0; ce1 = g1; ce2 = g2;
        h0 = i0; h1 = i1; h2 = i2;
    }
}

// ---------------- str_seg_prod: one structural segment of a product ------------------
__device__ __forceinline__ void str_seg_prod(int cnt, int st0, int hv,
        const int* __restrict__ srco, const float* __restrict__ xs,
        const float* __restrict__ wbase, float bs0, float bs1, float bs2,
        const float* __restrict__ Bm, int grp, int ln,
        float Stot[8], float* __restrict__ Lrow)
{
    if (cnt == 0) return;
    float ssum = 0.f;
    float SA[8]={0,0,0,0,0,0,0,0}, SB[8]={0,0,0,0,0,0,0,0}, SC[8]={0,0,0,0,0,0,0,0};
    int fa=0, fb=0, fc=0;

    for (int k0=0; k0<cnt; k0+=4) {
        bool act = (k0+grp) < cnt;
        int sv = (k0 == 0) ? hv : (act ? srco[st0+k0+grp] : 0);
        int o = (sv>>17)&3;
        float4 hA = make_float4(0.f,0.f,0.f,0.f), hB = hA;
        if (act) {
            const float* q = xs + (size_t)(sv & 0x1FFFF)*D + ln*8;
            hA = *(const float4*)q; hB = *(const float4*)(q+4);
        }
        const float* wq = wbase + o*128 + ln*8;
        float4 wA = *(const float4*)wq, wB = *(const float4*)(wq+4);
        float d = hA.x*wA.x + hA.y*wA.y + hA.z*wA.z + hA.w*wA.w
                + hB.x*wB.x + hB.y*wB.y + hB.z*wB.z + hB.w*wB.w;
        d = qsum(d);
        float wg = act ? __expf(d + ((o==0)?bs0:((o==1)?bs1:bs2))) : 0.f;
        ssum += wg;
        fa |= (int)(act && (o==0)); fb |= (int)(act && (o==1)); fc |= (int)(act && (o==2));
        float wg0=(o==0)?wg:0.f, wg1=(o==1)?wg:0.f, wg2=(o==2)?wg:0.f;
        #pragma unroll
        for (int j=0;j<8;j++){
            float hj = (j==0)?hA.x:(j==1)?hA.y:(j==2)?hA.z:(j==3)?hA.w:
                       (j==4)?hB.x:(j==5)?hB.y:(j==6)?hB.z:hB.w;
            SA[j] += wg0*hj; SB[j] += wg1*hj; SC[j] += wg2*hj;
        }
    }

    ssum += __shfl_xor(ssum, 16, 64);
    ssum += __shfl_xor(ssum, 32, 64);
    float inv = 1.f/(ssum + 1e-16f);

    int anyA = __any(fa), anyB = __any(fb), anyC = __any(fc);
    if (anyA) {
        #pragma unroll
        for (int j=0;j<8;j++){ SA[j] += __shfl_xor(SA[j],16,64); SA[j] += __shfl_xor(SA[j],32,64); }
    }
    if (anyB) {
        #pragma unroll
        for (int j=0;j<8;j++){ SB[j] += __shfl_xor(SB[j],16,64); SB[j] += __shfl_xor(SB[j],32,64); }
    }
    if (anyC) {
        #pragma unroll
        for (int j=0;j<8;j++){ SC[j] += __shfl_xor(SC[j],16,64); SC[j] += __shfl_xor(SC[j],32,64); }
    }
    #pragma unroll
    for (int j=0;j<8;j++) Stot[j] += (SA[j]+SB[j]+SC[j])*inv;

    float p0=0.f,p1=0.f,p2=0.f,p3=0.f;
    if (anyA) {
        const float* Bp = Bm + grp*4;
        #pragma unroll
        for (int j=0;j<8;j++){
            float4 b4 = *(const float4*)(Bp + (ln*8+j)*16);
            float v = SA[j];
            p0+=v*b4.x; p1+=v*b4.y; p2+=v*b4.z; p3+=v*b4.w;
        }
    }
    if (anyB) {
        const float* Bp = Bm + 2048 + grp*4;
        #pragma unroll
        for (int j=0;j<8;j++){
            float4 b4 = *(const float4*)(Bp + (ln*8+j)*16);
            float v = SB[j];
            p0+=v*b4.x; p1+=v*b4.y; p2+=v*b4.z; p3+=v*b4.w;
        }
    }
    if (anyC) {
        const float* Bp = Bm + 4096 + grp*4;
        #pragma unroll
        for (int j=0;j<8;j++){
            float4 b4 = *(const float4*)(Bp + (ln*8+j)*16);
            float v = SC[j];
            p0+=v*b4.x; p1+=v*b4.y; p2+=v*b4.z; p3+=v*b4.w;
        }
    }
    p0 = qsum(p0)*inv; p1 = qsum(p1)*inv; p2 = qsum(p2)*inv; p3 = qsum(p3)*inv;
    if (ln < 4) {
        float v = (ln==0)?p0:((ln==1)?p1:((ln==2)?p2:p3));
        Lrow[grp*4 + ln] = v;
    }
}

// ---------------- kagg_str v2 (R12): products skip-empty; cat/brand quad pipeline -----
__global__ __launch_bounds__(256) void kagg_str(Ptrs P,
        const int* __restrict__ starts, const int* __restrict__ counts,
        const int* __restrict__ srco,
        const float* __restrict__ w0, const float* __restrict__ bs,
        const float* __restrict__ Bm,
        float* __restrict__ Sout, float* __restrict__ Lb, int nWaves)
{
    int lane = threadIdx.x & 63;
    int wv = (blockIdx.x * 256 + threadIdx.x) >> 6;
    int grp = lane >> 4, ln = lane & 15;
    float bs0 = bs[0], bs1 = bs[1], bs2 = bs[2];

    for (int id = wv; id < NP + NC + NB; id += nWaves) {
        if (id < NP) {
            int n0 = id;
            int seg7 = 601000 + n0, seg9 = 703000 + n0;
            int cnt7 = counts[seg7], cnt9 = counts[seg9];
            if ((cnt7 | cnt9) == 0) continue;          // no RMW; L memset covers
            int st7 = starts[seg7] - cnt7, st9 = starts[seg9] - cnt9;
            int hv7 = (grp < cnt7) ? srco[st7+grp] : 0;
            int hv9 = (grp < cnt9) ? srco[st9+grp] : 0;

            float Stot[8] = {0,0,0,0,0,0,0,0};
            str_seg_prod(cnt7, st7, hv7, srco, P.x[2], w0 + 7*384,
                         bs0, bs1, bs2, Bm, grp, ln, Stot,
                         Lb + 3216000 + (size_t)n0*16);
            str_seg_prod(cnt9, st9, hv9, srco, P.x[3], w0 + 9*384,
                         bs0, bs1, bs2, Bm, grp, ln, Stot,
                         Lb + 4848000 + (size_t)n0*16);

            if (grp == 0) {
                float* Srow = Sout + (size_t)(100000+n0)*D + ln*8;
                float4 a = *(const float4*)Srow, b = *(const float4*)(Srow+4);
                *(float4*)Srow     = make_float4(a.x+Stot[0],a.y+Stot[1],a.z+Stot[2],a.w+Stot[3]);
                *(float4*)(Srow+4) = make_float4(b.x+Stot[4],b.y+Stot[5],b.z+Stot[6],b.w+Stot[7]);
            }
        } else {
            int T = (id < NP+NC) ? 2 : 3;
            int n0 = (T==2) ? (id-NP) : (id-(NP+NC));
            int et = (T==2) ? 6 : 8;
            int outRow = (T==2) ? (200000+n0) : (201000+n0);
            int seg = c_moff[et] + n0;
            int cnt = counts[seg];
            int st0 = starts[seg] - cnt;
            const float* xs = P.x[1];   // src = product for et6/et8
            const float* wbase = w0 + et*384;

            float ssum = 0.f;
            float SA[8]={0,0,0,0,0,0,0,0}, SB[8]={0,0,0,0,0,0,0,0}, SC[8]={0,0,0,0,0,0,0,0};
            int fa=0, fb=0, fc=0;

            // depth-1 quad pipeline
            int sv = 0;
            float4 hA = make_float4(0.f,0.f,0.f,0.f), hB = hA;
            if (grp < cnt) {
                sv = srco[st0+grp];
                const float* q = xs + (size_t)(sv & 0x1FFFF)*D + ln*8;
                hA = *(const float4*)q; hB = *(const float4*)(q+4);
            }
            for (int k0=0; k0<cnt; k0+=4) {
                int svn = 0;
                float4 nA = make_float4(0.f,0.f,0.f,0.f), nB = nA;
                if (k0+4+grp < cnt) {
                    svn = srco[st0+k0+4+grp];
                    const float* q = xs + (size_t)(svn & 0x1FFFF)*D + ln*8;
                    nA = *(const float4*)q; nB = *(const float4*)(q+4);
                }
                bool act = (k0+grp) < cnt;
                int o = (sv>>17)&3;
                const float* wq = wbase + o*128 + ln*8;
                float4 wA = *(const float4*)wq, wB = *(const float4*)(wq+4);
                float d = hA.x*wA.x + hA.y*wA.y + hA.z*wA.z + hA.w*wA.w
                        + hB.x*wB.x + hB.y*wB.y + hB.z*wB.z + hB.w*wB.w;
                d = qsum(d);
                float wg = act ? __expf(d + ((o==0)?bs0:((o==1)?bs1:bs2))) : 0.f;
                ssum += wg;
                fa |= (int)(act && (o==0)); fb |= (int)(act && (o==1)); fc |= (int)(act && (o==2));
                float wg0=(o==0)?wg:0.f, wg1=(o==1)?wg:0.f, wg2=(o==2)?wg:0.f;
                #pragma unroll
                for (int j=0;j<8;j++){
                    float hj = (j==0)?hA.x:(j==1)?hA.y:(j==2)?hA.z:(j==3)?hA.w:
                               (j==4)?hB.x:(j==5)?hB.y:(j==6)?hB.z:hB.w;
                    SA[j] += wg0*hj; SB[j] += wg1*hj; SC[j] += wg2*hj;
                }
                sv = svn; hA = nA; hB = nB;
            }

            ssum += __shfl_xor(ssum, 16, 64);
            ssum += __shfl_xor(ssum, 32, 64);
            float inv = 1.f/(ssum + 1e-16f);

            int anyA = __any(fa), anyB = __any(fb), anyC = __any(fc);
            if (anyA) {
                #pragma unroll
                for (int j=0;j<8;j++){ SA[j] += __shfl_xor(SA[j],16,64); SA[j] += __shfl_xor(SA[j],32,64); }
            }
            if (anyB) {
                #pragma unroll
                for (int j=0;j<8;j++){ SB[j] += __shfl_xor(SB[j],16,64); SB[j] += __shfl_xor(SB[j],32,64); }
            }
            if (anyC) {
                #pragma unroll
                for (int j=0;j<8;j++){ SC[j] += __shfl_xor(SC[j],16,64); SC[j] += __shfl_xor(SC[j],32,64); }
            }
            float Stot[8];
            #pragma unroll
            for (int j=0;j<8;j++) Stot[j] = (SA[j]+SB[j]+SC[j])*inv;

            float p0=0.f,p1=0.f,p2=0.f,p3=0.f;
            if (anyA) {
                const float* Bp = Bm + grp*4;
                #pragma unroll
                for (int j=0;j<8;j++){
                    float4 b4 = *(const float4*)(Bp + (ln*8+j)*16);
                    float v = SA[j];
                    p0+=v*b4.x; p1+=v*b4.y; p2+=v*b4.z; p3+=v*b4.w;
                }
            }
            if (anyB) {
                const float* Bp = Bm + 2048 + grp*4;
                #pragma unroll
                for (int j=0;j<8;j++){
                    float4 b4 = *(const float4*)(Bp + (ln*8+j)*16);
                    float v = SB[j];
                    p0+=v*b4.x; p1+=v*b4.y; p2+=v*b4.z; p3+=v*b4.w;
                }
            }
            if (anyC) {
                const float* Bp = Bm + 4096 + grp*4;
                #pragma unroll
                for (int j=0;j<8;j++){
                    float4 b4 = *(const float4*)(Bp + (ln*8+j)*16);
                    float v = SC[j];
                    p0+=v*b4.x; p1+=v*b4.y; p2+=v*b4.z; p3+=v*b4.w;
                }
            }
            p0 = qsum(p0)*inv; p1 = qsum(p1)*inv; p2 = qsum(p2)*inv; p3 = qsum(p3)*inv;

            int loff = (T==2) ? 3200000 : 4816000;
            if (ln < 4) {
                float v = (ln==0)?p0:((ln==1)?p1:((ln==2)?p2:p3));
                Lb[loff + (size_t)n0*16 + grp*4 + ln] = v;
            }
            if (grp == 0) {
                float* Srow = Sout + (size_t)outRow*D + ln*8;
                *(float4*)Srow     = make_float4(Stot[0],Stot[1],Stot[2],Stot[3]);
                *(float4*)(Srow+4) = make_float4(Stot[4],Stot[5],Stot[6],Stot[7]);
            }
        }
    }
}

// ---------------- K4 (fused): agg = W_base@S + sum A[p]@L_p, LN+ELU+residual ----------
__global__ __launch_bounds__(512, 1) void k4_final(Ptrs P,
        const float* __restrict__ WbT, const float* __restrict__ AT,
        const float* __restrict__ Lb,
        const float* __restrict__ gamma, const float* __restrict__ lbeta,
        float* __restrict__ out)
{
    __shared__ float st[128*132];   // S tile, stride 132
    __shared__ float wt[128*128];   // WbT tile: wt[i*128 + j]
    __shared__ float lt[128*52];    // L tile: lt[r*52 + pi*16 + k]
    int t = threadIdx.x;
    int b = blockIdx.x;
    int T, lb;
    if (b < K4_BU)      { T=0; lb=b; }
    else if (b < K4_BP) { T=1; lb=b-K4_BU; }
    else if (b < K4_BC) { T=2; lb=b-K4_BP; }
    else                { T=3; lb=b-K4_BC; }
    int r0 = lb*128;
    int rowStart = (T==0)?0:((T==1)?100000:((T==2)?200000:201000));
    int nRows    = (T==0)?NU:((T==1)?NP:((T==2)?NC:NB));
    const float* x = P.x[T];
    int nPairs = g_nGrp[T];

    for (int idx=t; idx<4096; idx+=512)
        *(float4*)&wt[idx*4] = *(const float4*)&WbT[idx*4];
    for (int idx=t; idx<4096; idx+=512){
        int r = idx>>5, i4 = idx&31;
        int lr = r0 + r;
        float4 v = (lr < nRows) ? *(const float4*)&out[(size_t)(rowStart+lr)*D + i4*4]
                                : make_float4(0.f,0.f,0.f,0.f);
        *(float4*)&st[r*132 + i4*4] = v;
    }
    for (int pi=0; pi<nPairs; ++pi){
        int lo = g_Loff[T][pi];
        int r = t>>2, q = t&3;
        int lr = r0 + r;
        float4 v = (lr < nRows) ? *(const float4*)&Lb[lo + (size_t)lr*16 + q*4]
                                : make_float4(0.f,0.f,0.f,0.f);
        *(float4*)&lt[r*52 + pi*16 + q*4] = v;
    }
    __syncthreads();

    int cg = t & 15, rg = t >> 4;
    float acc[4][8];
    #pragma unroll
    for (int a=0;a<4;a++)
        #pragma unroll
        for (int c=0;c<8;c++) acc[a][c]=0.f;

    for (int i4=0; i4<32; ++i4){
        float4 sv0 = *(const float4*)&st[(rg*4+0)*132 + i4*4];
        float4 sv1 = *(const float4*)&st[(rg*4+1)*132 + i4*4];
        float4 sv2 = *(const float4*)&st[(rg*4+2)*132 + i4*4];
        float4 sv3 = *(const float4*)&st[(rg*4+3)*132 + i4*4];
        #pragma unroll
        for (int q=0;q<4;q++){
            float4 wA = *(const float4*)&wt[(i4*4+q)*128 + cg*4];
            float4 wB = *(const float4*)&wt[(i4*4+q)*128 + 64 + cg*4];
            float sq[4];
            sq[0] = (q==0)?sv0.x:(q==1)?sv0.y:(q==2)?sv0.z:sv0.w;
            sq[1] = (q==0)?sv1.x:(q==1)?sv1.y:(q==2)?sv1.z:sv1.w;
            sq[2] = (q==0)?sv2.x:(q==1)?sv2.y:(q==2)?sv2.z:sv2.w;
            sq[3] = (q==0)?sv3.x:(q==1)?sv3.y:(q==2)?sv3.z:sv3.w;
            #pragma unroll
            for (int rr=0;rr<4;rr++){
                acc[rr][0] += sq[rr]*wA.x;
                acc[rr][1] += sq[rr]*wA.y;
                acc[rr][2] += sq[rr]*wA.z;
                acc[rr][3] += sq[rr]*wA.w;
                acc[rr][4] += sq[rr]*wB.x;
                acc[rr][5] += sq[rr]*wB.y;
                acc[rr][6] += sq[rr]*wB.z;
                acc[rr][7] += sq[rr]*wB.w;
            }
        }
    }

    for (int pi=0; pi<nPairs; ++pi){
        int ai = g_ai[T][pi];
        const float* Ap = AT + ai*2048;
        #pragma unroll 4
        for (int r=0;r<16;++r){
            float4 aA = *(const float4*)&Ap[r*128 + cg*4];
            float4 aB = *(const float4*)&Ap[r*128 + 64 + cg*4];
            float lv[4];
            #pragma unroll
            for (int rr=0;rr<4;rr++) lv[rr] = lt[(rg*4+rr)*52 + pi*16 + r];
            #pragma unroll
            for (int rr=0;rr<4;rr++){
                acc[rr][0] += lv[rr]*aA.x;
                acc[rr][1] += lv[rr]*aA.y;
                acc[rr][2] += lv[rr]*aA.z;
                acc[rr][3] += lv[rr]*aA.w;
                acc[rr][4] += lv[rr]*aB.x;
                acc[rr][5] += lv[rr]*aB.y;
                acc[rr][6] += lv[rr]*aB.z;
                acc[rr][7] += lv[rr]*aB.w;
            }
        }
    }

    int jA = cg*4, jB = 64 + cg*4;
    float4 gA = *(const float4*)&gamma[jA], gB = *(const float4*)&gamma[jB];
    float4 bA = *(const float4*)&lbeta[jA], bB = *(const float4*)&lbeta[jB];
    float gv[8] = {gA.x,gA.y,gA.z,gA.w,gB.x,gB.y,gB.z,gB.w};
    float bv[8] = {bA.x,bA.y,bA.z,bA.w,bB.x,bB.y,bB.z,bB.w};

    #pragma unroll
    for (int rr=0;rr<4;rr++){
        int lr = r0 + rg*4 + rr;
        float lsum=0.f, lsq=0.f;
        #pragma unroll
        for (int c=0;c<8;c++){ lsum += acc[rr][c]; lsq += acc[rr][c]*acc[rr][c]; }
        #pragma unroll
        for (int mm=1; mm<16; mm<<=1){ lsum += __shfl_xor(lsum,mm,64); lsq += __shfl_xor(lsq,mm,64); }
        if (lr >= nRows) continue;
        float mu = lsum*(1.f/128.f);
        float var = lsq*(1.f/128.f) - mu*mu;
        float rstd = rsqrtf(var + 1e-5f);
        const float* xr = x + (size_t)lr*D;
        float4 xA = *(const float4*)(xr+jA), xB = *(const float4*)(xr+jB);
        float xv[8] = {xA.x,xA.y,xA.z,xA.w,xB.x,xB.y,xB.z,xB.w};
        float ov[8];
        #pragma unroll
        for (int c=0;c<8;c++){
            float hn = (acc[rr][c]-mu)*rstd*gv[c] + bv[c];
            float z = hn + xv[c];
            ov[c] = z > 0.f ? z : expm1f(z);
        }
        float* orow = out + (size_t)(rowStart+lr)*D;
        *(float4*)(orow+jA) = make_float4(ov[0],ov[1],ov[2],ov[3]);
        *(float4*)(orow+jB) = make_float4(ov[4],ov[5],ov[6],ov[7]);
    }
}

extern "C" void kernel_launch(void* const* d_in, const int* in_sizes, int n_in,
                              void* d_out, int out_size, void* d_ws, size_t ws_size,
                              hipStream_t stream)
{
    (void)in_sizes; (void)n_in; (void)out_size; (void)ws_size;
    Ptrs P;
    P.x[0] = (const float*)d_in[0];   // x_user
    P.x[1] = (const float*)d_in[1];   // x_product
    P.x[2] = (const float*)d_in[2];   // x_category
    P.x[3] = (const float*)d_in[3];   // x_brand
    P.ei[0] = (const int*)d_in[4];    // view
    P.ei[1] = (const int*)d_in[5];    // cart
    P.ei[2] = (const int*)d_in[6];    // purchase
    P.ei[3] = (const int*)d_in[7];    // rev_view
    P.ei[4] = (const int*)d_in[8];    // rev_cart
    P.ei[5] = (const int*)d_in[9];    // rev_purchase
    P.ei[6] = (const int*)d_in[10];   // belongs_to
    P.attr[0] = (const int*)d_in[11];
    P.ei[7] = (const int*)d_in[12];   // contains
    P.attr[1] = (const int*)d_in[13];
    P.ei[8] = (const int*)d_in[14];   // producedBy
    P.attr[2] = (const int*)d_in[15];
    P.ei[9] = (const int*)d_in[16];   // brands
    P.attr[3] = (const int*)d_in[17];
    const float* Wb    = (const float*)d_in[18];
    const float* A     = (const float*)d_in[19];
    const float* B     = (const float*)d_in[20];
    const float* behW  = (const float*)d_in[22];
    const float* a_att = (const float*)d_in[23];
    const float* gamma = (const float*)d_in[24];
    const float* lbeta = (const float*)d_in[25];
    float* wsf = (float*)d_ws;
    float* out = (float*)d_out;

    int* ip     = (int*)(wsf + OFF_INT);
    int* counts = ip;
    int* starts = ip + 803000;
    int* srco   = ip + 1606000;
    int* bsums  = (int*)wsf;          // overlays product L-group0 (fully rewritten by kagg_beh)

    hipMemsetAsync(counts, 0, (size_t)NSEG*sizeof(int), stream);
    // zero only L regions that may be skipped (product structural groups)
    hipMemsetAsync(wsf + 3216000, 0, (size_t)(6448000-3216000)*sizeof(float), stream);

    k0_tables<<<1, 256, 0, stream>>>(Wb, A, B, behW, a_att, wsf+OFF_W0, wsf+OFF_BS);
    ktrans<<<96, 256, 0, stream>>>(Wb, A, wsf+OFF_WT, wsf+OFF_AT);
    khist<<<3125, 256, 0, stream>>>(P, counts);
    kscan1<<<NBLK, 256, 0, stream>>>(counts, starts, bsums);
    kscan2<<<1, 256, 0, stream>>>(bsums);
    kscan3<<<NBLK, 256, 0, stream>>>(starts, bsums);
    kscatter<<<3125, 256, 0, stream>>>(P, starts, srco);

    kagg_beh<<<4096, 256, 0, stream>>>(P, starts, counts, srco,
                                       wsf+OFF_W0, B, out, wsf+OFF_L, 4096*4);
    kagg_str<<<1024, 256, 0, stream>>>(P, starts, counts, srco,
                                       wsf+OFF_W0, wsf+OFF_BS, B, out, wsf+OFF_L, 1024*4);

    k4_final<<<K4_BT, 512, 0, stream>>>(P, wsf+OFF_WT, wsf+OFF_AT, wsf+OFF_L,
                                        gamma, lbeta, out);
}

// Round 18
// 854.435 us; speedup vs baseline: 1.0670x; 1.0065x over previous
//
#include <hip/hip_runtime.h>
#include <hip/hip_bf16.h>
#include <math.h>

#define D 128

// problem sizes (fixed by reference)
#define NU 100000
#define NP 100000
#define NC 1000
#define NB 2000
#define NTOT 203000
#define EB 100000
#define ES 50000
#define ETOT 800000
#define NSEG 803000
#define NBLK 785          // ceil(NSEG/1024)
#define NTOTB 200000      // behavioral dst nodes (user+product)

// ws layout (float offsets)
#define OFF_L    0            // 6448000 floats: low-rank accumulators
#define OFF_W0   6448000      // 10*3*128
#define OFF_BS   6451840      // 16 (bs[4])
#define OFF_WT   7251856      // 16384 floats: W_base^T
#define OFF_AT   7268240      // 8192 floats: A^T per phi
#define OFF_INT  7276432      // int region
// ints relative to (int*)(wsf+OFF_INT):
//   counts @ 0        (803000)
//   starts @ 803000   (803000)  -- after kscatter: segment END
//   srco   @ 1606000  (800000)  -- src | o<<17 | et<<19, CSR order (o = beta for behavioral)

// per-edge-type metadata
__constant__ int c_srcT[10]   = {0,0,0,1,1,1,1,2,1,3};
__constant__ int c_phi [10]   = {0,0,0,1,1,1,1,2,1,3};
__constant__ int c_beta[10]   = {0,1,2,0,1,2,-1,-1,-1,-1};
__constant__ int c_E   [10]   = {EB,EB,EB,EB,EB,EB,ES,ES,ES,ES};
__constant__ int c_moff[10]   = {0,100000,200000,300000,400000,500000,600000,601000,701000,703000};

__constant__ int g_nGrp[4]    = {1,3,1,1};
__constant__ int g_Loff[4][3] = {{1600000,0,0},{0,3216000,4848000},{3200000,0,0},{4816000,0,0}};
__constant__ int g_ai[4][3]   = {{1,0,0},{0,2,3},{1,0,0},{1,0,0}};

// k4 fused-launch block ranges: U 782, P 782, C 8, B 16
#define K4_BU 782
#define K4_BP 1564
#define K4_BC 1572
#define K4_BT 1588

struct Ptrs {
    const float* x[4];
    const int*   ei[10];
    const int*   attr[4];   // for edge types 6..9
};

__device__ __forceinline__ void decode_et(int eflat, int& et, int& le) {
    if (eflat < 600000) { et = eflat / 100000; le = eflat - et * 100000; }
    else { int r = eflat - 600000; int q = r / 50000; et = 6 + q; le = r - q * 50000; }
}

// DPP-based add of permuted value: compile-time ctrl (required by the builtin)
template<int CTRL>
__device__ __forceinline__ float dpp_add(float v) {
    int x = __builtin_amdgcn_update_dpp(0, __float_as_int(v), CTRL, 0xF, 0xF, true);
    return v + __int_as_float(x);
}

// sum across the 16-lane quarter-wave group (DPP tree: pairs -> quads -> row)
// result broadcast to all 16 lanes of the row
__device__ __forceinline__ float qsum(float v) {
    v = dpp_add<0xB1>(v);    // quad_perm [1,0,3,2]  (xor 1)
    v = dpp_add<0x4E>(v);    // quad_perm [2,3,0,1]  (xor 2)
    v = dpp_add<0x124>(v);   // row_ror:4  -> sum of adjacent quad pair
    v = dpp_add<0x128>(v);   // row_ror:8  -> full 16-lane sum
    return v;
}

// ---------------- K0: w0 tables + bs ----------------
__global__ void k0_tables(const float* __restrict__ Wb, const float* __restrict__ A,
                          const float* __restrict__ B, const float* __restrict__ behW,
                          const float* __restrict__ a_att,
                          float* __restrict__ w0, float* __restrict__ bs_out)
{
    __shared__ float a0[128];
    __shared__ float c0[128];
    __shared__ float g0[4][16];
    int t = threadIdx.x;
    if (t < 128) a0[t] = a_att[t];
    __syncthreads();
    if (t < 128) {
        float s0=0.f;
        for (int j=0;j<128;j++) s0 += Wb[j*128+t]*a0[j];
        c0[t]=s0;
    } else if (t < 192) {
        int q=t-128, p=q>>4, r=q&15;
        float s0=0.f;
        for (int i=0;i<128;i++) s0 += A[p*2048+i*16+r]*a0[i];
        g0[p][r]=s0;
    } else if (t < 196) {
        int b=t-192; float s=0.f;
        for (int i=0;i<128;i++) s += behW[b*128+i]*a_att[384+i];
        bs_out[b]=s;
    }
    __syncthreads();
    if (t < 128) {
        for (int et=0; et<10; ++et) {
            int phi=c_phi[et], beta=c_beta[et];
            if (beta >= 0) {
                float s0=c0[t];
                for (int r=0;r<16;r++) s0 += B[beta*2048+t*16+r]*g0[phi][r];
                w0[et*384+t]=s0; w0[et*384+128+t]=s0; w0[et*384+256+t]=s0;
            } else {
                for (int o=0;o<3;o++){
                    float s0=c0[t];
                    for (int r=0;r<16;r++) s0 += B[o*2048+t*16+r]*g0[phi][r];
                    w0[et*384+o*128+t]=s0;
                }
            }
        }
    }
}

// ---------------- ktrans: W_base^T and A^T precompute ----------------
__global__ __launch_bounds__(256) void ktrans(const float* __restrict__ Wb,
        const float* __restrict__ A, float* __restrict__ WbT, float* __restrict__ AT)
{
    int idx = blockIdx.x*256 + threadIdx.x;
    if (idx < 16384) { int i = idx>>7, j = idx&127; WbT[i*128+j] = Wb[j*128+i]; }
    int idx2 = idx - 16384;
    if (idx2 >= 0 && idx2 < 8192) {
        int p = idx2>>11, rem = idx2&2047, r = rem>>7, j = rem&127;
        AT[idx2] = A[p*2048 + j*16 + r];
    }
}

// ---------------- CSR build ----------------
__global__ __launch_bounds__(256) void khist(Ptrs P, int* __restrict__ counts)
{
    int eflat = blockIdx.x*256 + threadIdx.x;
    if (eflat >= ETOT) return;
    int et, le; decode_et(eflat, et, le);
    int dst = P.ei[et][c_E[et] + le];
    atomicAdd(&counts[c_moff[et] + dst], 1);
}

__global__ __launch_bounds__(256) void kscan1(const int* __restrict__ cnt,
                                              int* __restrict__ st, int* __restrict__ bsums)
{
    __shared__ int lds[256];
    int t = threadIdx.x, b = blockIdx.x;
    int base = b*1024 + t*4;
    int v0 = (base   < NSEG) ? cnt[base]   : 0;
    int v1 = (base+1 < NSEG) ? cnt[base+1] : 0;
    int v2 = (base+2 < NSEG) ? cnt[base+2] : 0;
    int v3 = (base+3 < NSEG) ? cnt[base+3] : 0;
    int s = v0+v1+v2+v3;
    lds[t] = s; __syncthreads();
    for (int off=1; off<256; off<<=1){
        int xv = (t>=off) ? lds[t-off] : 0;
        __syncthreads();
        lds[t] += xv;
        __syncthreads();
    }
    int incl = lds[t];
    int p = incl - s;
    if (t==255) bsums[b] = incl;
    if (base   < NSEG) st[base]   = p; p += v0;
    if (base+1 < NSEG) st[base+1] = p; p += v1;
    if (base+2 < NSEG) st[base+2] = p; p += v2;
    if (base+3 < NSEG) st[base+3] = p;
}

__global__ __launch_bounds__(256) void kscan2(int* __restrict__ bsums)
{
    __shared__ int lds[256];
    int t = threadIdx.x;
    int base = t*4;
    int v0 = (base   < NBLK) ? bsums[base]   : 0;
    int v1 = (base+1 < NBLK) ? bsums[base+1] : 0;
    int v2 = (base+2 < NBLK) ? bsums[base+2] : 0;
    int v3 = (base+3 < NBLK) ? bsums[base+3] : 0;
    int s = v0+v1+v2+v3;
    lds[t] = s; __syncthreads();
    for (int off=1; off<256; off<<=1){
        int xv = (t>=off) ? lds[t-off] : 0;
        __syncthreads();
        lds[t] += xv;
        __syncthreads();
    }
    int p = lds[t] - s;
    if (base   < NBLK) bsums[base]   = p; p += v0;
    if (base+1 < NBLK) bsums[base+1] = p; p += v1;
    if (base+2 < NBLK) bsums[base+2] = p; p += v2;
    if (base+3 < NBLK) bsums[base+3] = p;
}

__global__ __launch_bounds__(256) void kscan3(int* __restrict__ st, const int* __restrict__ bsums)
{
    int t = threadIdx.x, b = blockIdx.x;
    int add = bsums[b];
    int base = b*1024 + t*4;
    #pragma unroll
    for (int j=0;j<4;j++)
        if (base+j < NSEG) st[base+j] += add;
}

__global__ __launch_bounds__(256) void kscatter(Ptrs P, int* __restrict__ st, int* __restrict__ srco)
{
    int eflat = blockIdx.x*256 + threadIdx.x;
    if (eflat >= ETOT) return;
    int et, le; decode_et(eflat, et, le);
    const int* ei = P.ei[et];
    int E = c_E[et];
    int src = ei[le], dst = ei[E+le];
    int o;
    if (et >= 6) { int a = P.attr[et-6][le]; o = min(max(a,0),2); }
    else o = c_beta[et];
    int pos = atomicAdd(&st[c_moff[et] + dst], 1);
    srco[pos] = src | (o<<17) | (et<<19);
}
// after kscatter: st[seg] == segment end; start = st[seg] - counts[seg]

// ---------------- kagg_beh v5: R9 body + cross-node scalar pipeline -------------------
// Pipeline: seginfo issued 2 nodes ahead, srco-heads 1 node ahead -> only the x-gather
// round stays exposed per node. qsum is DPP (no DS traffic).
__global__ __launch_bounds__(256) void kagg_beh(Ptrs P,
        const int* __restrict__ starts, const int* __restrict__ counts,
        const int* __restrict__ srco,
        const float* __restrict__ w0, const float* __restrict__ Bm,
        float* __restrict__ Sout, float* __restrict__ Lb, int nWaves)
{
    int lane = threadIdx.x & 63;
    int wv = (blockIdx.x * 256 + threadIdx.x) >> 6;
    int grp = lane >> 4, ln = lane & 15;

    if (wv >= NTOTB) return;

    // --- prologue: seginfo for node j (=wv), heads for j, seginfo for j+1 ---
    int a0,a1,a2,b0,b1,b2;          // cnt/end for current node j
    {
        int nid = wv;
        int sg = ((nid < NU) ? (300000 + nid) : (nid - NU));
        a0 = counts[sg];         a1 = counts[sg+100000];  a2 = counts[sg+200000];
        b0 = starts[sg];         b1 = starts[sg+100000];  b2 = starts[sg+200000];
    }
    int h0=0, h1=0, h2=0;           // srco heads for current node j
    if (grp < a0) h0 = srco[b0-a0+grp];
    if (grp < a1) h1 = srco[b1-a1+grp];
    if (grp < a2) h2 = srco[b2-a2+grp];
    int cc0=0,cc1=0,cc2=0, ce0=0,ce1=0,ce2=0;   // seginfo for node j+1
    if (wv + nWaves < NTOTB) {
        int nid = wv + nWaves;
        int sg = ((nid < NU) ? (300000 + nid) : (nid - NU));
        cc0 = counts[sg];        cc1 = counts[sg+100000]; cc2 = counts[sg+200000];
        ce0 = starts[sg];        ce1 = starts[sg+100000]; ce2 = starts[sg+200000];
    }

    for (int nid = wv; nid < NTOTB; nid += nWaves) {
        int T = (nid < NU) ? 0 : 1;
        int n0 = (T == 0) ? nid : nid - NU;
        int etBase = (T == 0) ? 3 : 0;
        const float* xs = P.x[1 - T];

        int cnt0 = a0, cnt1 = a1, cnt2 = a2;
        int sa0 = b0-a0, sa1 = b1-a1, sa2 = b2-a2;
        int sv1 = h1, sv2 = h2;

        // step 1: issue seginfo loads for node j+2 (consumed a full body later)
        int f0=0,f1=0,f2=0, g0=0,g1=0,g2=0;
        {
            int nid2 = nid + 2*nWaves;
            if (nid2 < NTOTB) {
                int sg = ((nid2 < NU) ? (300000 + nid2) : (nid2 - NU));
                f0 = counts[sg];     f1 = counts[sg+100000]; f2 = counts[sg+200000];
                g0 = starts[sg];     g1 = starts[sg+100000]; g2 = starts[sg+200000];
            }
        }

        // step 2: x head prefetch for segment 0 (h0 ready from last iteration)
        float4 pA = make_float4(0.f,0.f,0.f,0.f), pB = pA;
        if (grp < cnt0) {
            const float* q = xs + (size_t)(h0 & 0x1FFFF)*D + ln*8;
            pA = *(const float4*)q; pB = *(const float4*)(q+4);
        }

        // step 3: issue srco-head loads for node j+1 (its seginfo landed last iteration)
        int i0=0, i1=0, i2=0;
        if (nid + nWaves < NTOTB) {
            if (grp < cc0) i0 = srco[ce0-cc0+grp];
            if (grp < cc1) i1 = srco[ce1-cc1+grp];
            if (grp < cc2) i2 = srco[ce2-cc2+grp];
        }

        // step 4: body (R9 structure)
        float Stot[8] = {0,0,0,0,0,0,0,0};
        float Lq0=0.f, Lq1=0.f, Lq2=0.f, Lq3=0.f;

        for (int s=0; s<3; ++s) {
            int cnt = (s==0)?cnt0:((s==1)?cnt1:cnt2);
            int st0 = (s==0)?sa0:((s==1)?sa1:sa2);
            float4 cA = pA, cB = pB;
            // rolling prefetch: next segment's first-quad x
            pA = make_float4(0.f,0.f,0.f,0.f); pB = pA;
            if (s == 0) {
                if (grp < cnt1) {
                    const float* q = xs + (size_t)(sv1 & 0x1FFFF)*D + ln*8;
                    pA = *(const float4*)q; pB = *(const float4*)(q+4);
                }
            } else if (s == 1) {
                if (grp < cnt2) {
                    const float* q = xs + (size_t)(sv2 & 0x1FFFF)*D + ln*8;
                    pA = *(const float4*)q; pB = *(const float4*)(q+4);
                }
            }
            if (cnt == 0) continue;
            int et = etBase + s;
            const float* wq = w0 + et*384 + ln*8;
            float4 wA = *(const float4*)wq, wB = *(const float4*)(wq+4);

            float ssum = 0.f;
            float SA[8] = {0,0,0,0,0,0,0,0};

            for (int k0=0; k0<cnt; k0+=4) {
                bool act = (k0+grp) < cnt;
                if (k0 > 0) {
                    cA = make_float4(0.f,0.f,0.f,0.f); cB = cA;
                    if (act) {
                        int sv = srco[st0+k0+grp];
                        const float* q = xs + (size_t)(sv & 0x1FFFF)*D + ln*8;
                        cA = *(const float4*)q; cB = *(const float4*)(q+4);
                    }
                }
                float d = cA.x*wA.x + cA.y*wA.y + cA.z*wA.z + cA.w*wA.w
                        + cB.x*wB.x + cB.y*wB.y + cB.z*wB.z + cB.w*wB.w;
                d = qsum(d);
                float wg = act ? __expf(d) : 0.f;   // no-max softmax (shift-invariant)
                ssum += wg;
                SA[0]+=wg*cA.x; SA[1]+=wg*cA.y; SA[2]+=wg*cA.z; SA[3]+=wg*cA.w;
                SA[4]+=wg*cB.x; SA[5]+=wg*cB.y; SA[6]+=wg*cB.z; SA[7]+=wg*cB.w;
            }
            // cross-slot totals
            ssum += __shfl_xor(ssum, 16, 64);
            ssum += __shfl_xor(ssum, 32, 64);
            float inv = 1.f/(ssum + 1e-16f);
            #pragma unroll
            for (int j=0;j<8;j++){ SA[j] += __shfl_xor(SA[j],16,64); SA[j] += __shfl_xor(SA[j],32,64); }
            #pragma unroll
            for (int j=0;j<8;j++) Stot[j] += SA[j]*inv;

            // B[beta=s]^T SA : cols grp*4..+3, rows ln*8..+7
            const float* Bp = Bm + s*2048 + grp*4;
            float p0=0.f,p1=0.f,p2=0.f,p3=0.f;
            #pragma unroll
            for (int j=0;j<8;j++){
                float4 b4 = *(const float4*)(Bp + (ln*8+j)*16);
                float v = SA[j];
                p0+=v*b4.x; p1+=v*b4.y; p2+=v*b4.z; p3+=v*b4.w;
            }
            Lq0 += qsum(p0)*inv; Lq1 += qsum(p1)*inv;
            Lq2 += qsum(p2)*inv; Lq3 += qsum(p3)*inv;
        }

        // step 5: stores
        if (grp == 0) {
            float* Srow = Sout + (size_t)nid*D + ln*8;
            *(float4*)Srow     = make_float4(Stot[0],Stot[1],Stot[2],Stot[3]);
            *(float4*)(Srow+4) = make_float4(Stot[4],Stot[5],Stot[6],Stot[7]);
        }
        if (ln < 4) {
            float v = (ln==0)?Lq0:((ln==1)?Lq1:((ln==2)?Lq2:Lq3));
            int loff = (T==0) ? 1600000 : 0;
            Lb[loff + (size_t)n0*16 + grp*4 + ln] = v;
        }

        // step 6: rotate pipeline state
        a0 = cc0; a1 = cc1; a2 = cc2;
        b0 = ce0; b1 = ce1; b2 = ce2;
        cc0 = f0; cc1 = f1; cc2 = f2;
        ce0 = g0; ce1 = g1; ce2 = g2;
        h0 = i0; h1 = i1; h2 = i2;
    }
}

// ---------------- str_seg_prod: one structural segment of a product ------------------
__device__ __forceinline__ void str_seg_prod(int cnt, int st0, int hv,
        const int* __restrict__ srco, const float* __restrict__ xs,
        const float* __restrict__ wbase, float bs0, float bs1, float bs2,
        const float* __restrict__ Bm, int grp, int ln,
        float Stot[8], float* __restrict__ Lrow)
{
    if (cnt == 0) return;
    float ssum = 0.f;
    float SA[8]={0,0,0,0,0,0,0,0}, SB[8]={0,0,0,0,0,0,0,0}, SC[8]={0,0,0,0,0,0,0,0};
    int fa=0, fb=0, fc=0;

    for (int k0=0; k0<cnt; k0+=4) {
        bool act = (k0+grp) < cnt;
        int sv = (k0 == 0) ? hv : (act ? srco[st0+k0+grp] : 0);
        int o = (sv>>17)&3;
        float4 hA = make_float4(0.f,0.f,0.f,0.f), hB = hA;
        if (act) {
            const float* q = xs + (size_t)(sv & 0x1FFFF)*D + ln*8;
            hA = *(const float4*)q; hB = *(const float4*)(q+4);
        }
        const float* wq = wbase + o*128 + ln*8;
        float4 wA = *(const float4*)wq, wB = *(const float4*)(wq+4);
        float d = hA.x*wA.x + hA.y*wA.y + hA.z*wA.z + hA.w*wA.w
                + hB.x*wB.x + hB.y*wB.y + hB.z*wB.z + hB.w*wB.w;
        d = qsum(d);
        float wg = act ? __expf(d + ((o==0)?bs0:((o==1)?bs1:bs2))) : 0.f;
        ssum += wg;
        fa |= (int)(act && (o==0)); fb |= (int)(act && (o==1)); fc |= (int)(act && (o==2));
        float wg0=(o==0)?wg:0.f, wg1=(o==1)?wg:0.f, wg2=(o==2)?wg:0.f;
        #pragma unroll
        for (int j=0;j<8;j++){
            float hj = (j==0)?hA.x:(j==1)?hA.y:(j==2)?hA.z:(j==3)?hA.w:
                       (j==4)?hB.x:(j==5)?hB.y:(j==6)?hB.z:hB.w;
            SA[j] += wg0*hj; SB[j] += wg1*hj; SC[j] += wg2*hj;
        }
    }

    ssum += __shfl_xor(ssum, 16, 64);
    ssum += __shfl_xor(ssum, 32, 64);
    float inv = 1.f/(ssum + 1e-16f);

    int anyA = __any(fa), anyB = __any(fb), anyC = __any(fc);
    if (anyA) {
        #pragma unroll
        for (int j=0;j<8;j++){ SA[j] += __shfl_xor(SA[j],16,64); SA[j] += __shfl_xor(SA[j],32,64); }
    }
    if (anyB) {
        #pragma unroll
        for (int j=0;j<8;j++){ SB[j] += __shfl_xor(SB[j],16,64); SB[j] += __shfl_xor(SB[j],32,64); }
    }
    if (anyC) {
        #pragma unroll
        for (int j=0;j<8;j++){ SC[j] += __shfl_xor(SC[j],16,64); SC[j] += __shfl_xor(SC[j],32,64); }
    }
    #pragma unroll
    for (int j=0;j<8;j++) Stot[j] += (SA[j]+SB[j]+SC[j])*inv;

    float p0=0.f,p1=0.f,p2=0.f,p3=0.f;
    if (anyA) {
        const float* Bp = Bm + grp*4;
        #pragma unroll
        for (int j=0;j<8;j++){
            float4 b4 = *(const float4*)(Bp + (ln*8+j)*16);
            float v = SA[j];
            p0+=v*b4.x; p1+=v*b4.y; p2+=v*b4.z; p3+=v*b4.w;
        }
    }
    if (anyB) {
        const float* Bp = Bm + 2048 + grp*4;
        #pragma unroll
        for (int j=0;j<8;j++){
            float4 b4 = *(const float4*)(Bp + (ln*8+j)*16);
            float v = SB[j];
            p0+=v*b4.x; p1+=v*b4.y; p2+=v*b4.z; p3+=v*b4.w;
        }
    }
    if (anyC) {
        const float* Bp = Bm + 4096 + grp*4;
        #pragma unroll
        for (int j=0;j<8;j++){
            float4 b4 = *(const float4*)(Bp + (ln*8+j)*16);
            float v = SC[j];
            p0+=v*b4.x; p1+=v*b4.y; p2+=v*b4.z; p3+=v*b4.w;
        }
    }
    p0 = qsum(p0)*inv; p1 = qsum(p1)*inv; p2 = qsum(p2)*inv; p3 = qsum(p3)*inv;
    if (ln < 4) {
        float v = (ln==0)?p0:((ln==1)?p1:((ln==2)?p2:p3));
        Lrow[grp*4 + ln] = v;
    }
}

// ---------------- kagg_str v2 (R12): products skip-empty; cat/brand quad pipeline -----
__global__ __launch_bounds__(256) void kagg_str(Ptrs P,
        const int* __restrict__ starts, const int* __restrict__ counts,
        const int* __restrict__ srco,
        const float* __restrict__ w0, const float* __restrict__ bs,
        const float* __restrict__ Bm,
        float* __restrict__ Sout, float* __restrict__ Lb, int nWaves)
{
    int lane = threadIdx.x & 63;
    int wv = (blockIdx.x * 256 + threadIdx.x) >> 6;
    int grp = lane >> 4, ln = lane & 15;
    float bs0 = bs[0], bs1 = bs[1], bs2 = bs[2];

    for (int id = wv; id < NP + NC + NB; id += nWaves) {
        if (id < NP) {
            int n0 = id;
            int seg7 = 601000 + n0, seg9 = 703000 + n0;
            int cnt7 = counts[seg7], cnt9 = counts[seg9];
            if ((cnt7 | cnt9) == 0) continue;          // no RMW; L memset covers
            int st7 = starts[seg7] - cnt7, st9 = starts[seg9] - cnt9;
            int hv7 = (grp < cnt7) ? srco[st7+grp] : 0;
            int hv9 = (grp < cnt9) ? srco[st9+grp] : 0;

            float Stot[8] = {0,0,0,0,0,0,0,0};
            str_seg_prod(cnt7, st7, hv7, srco, P.x[2], w0 + 7*384,
                         bs0, bs1, bs2, Bm, grp, ln, Stot,
                         Lb + 3216000 + (size_t)n0*16);
            str_seg_prod(cnt9, st9, hv9, srco, P.x[3], w0 + 9*384,
                         bs0, bs1, bs2, Bm, grp, ln, Stot,
                         Lb + 4848000 + (size_t)n0*16);

            if (grp == 0) {
                float* Srow = Sout + (size_t)(100000+n0)*D + ln*8;
                float4 a = *(const float4*)Srow, b = *(const float4*)(Srow+4);
                *(float4*)Srow     = make_float4(a.x+Stot[0],a.y+Stot[1],a.z+Stot[2],a.w+Stot[3]);
                *(float4*)(Srow+4) = make_float4(b.x+Stot[4],b.y+Stot[5],b.z+Stot[6],b.w+Stot[7]);
            }
        } else {
            int T = (id < NP+NC) ? 2 : 3;
            int n0 = (T==2) ? (id-NP) : (id-(NP+NC));
            int et = (T==2) ? 6 : 8;
            int outRow = (T==2) ? (200000+n0) : (201000+n0);
            int seg = c_moff[et] + n0;
            int cnt = counts[seg];
            int st0 = starts[seg] - cnt;
            const float* xs = P.x[1];   // src = product for et6/et8
            const float* wbase = w0 + et*384;

            float ssum = 0.f;
            float SA[8]={0,0,0,0,0,0,0,0}, SB[8]={0,0,0,0,0,0,0,0}, SC[8]={0,0,0,0,0,0,0,0};
            int fa=0, fb=0, fc=0;

            // depth-1 quad pipeline
            int sv = 0;
            float4 hA = make_float4(0.f,0.f,0.f,0.f), hB = hA;
            if (grp < cnt) {
                sv = srco[st0+grp];
                const float* q = xs + (size_t)(sv & 0x1FFFF)*D + ln*8;
                hA = *(const float4*)q; hB = *(const float4*)(q+4);
            }
            for (int k0=0; k0<cnt; k0+=4) {
                int svn = 0;
                float4 nA = make_float4(0.f,0.f,0.f,0.f), nB = nA;
                if (k0+4+grp < cnt) {
                    svn = srco[st0+k0+4+grp];
                    const float* q = xs + (size_t)(svn & 0x1FFFF)*D + ln*8;
                    nA = *(const float4*)q; nB = *(const float4*)(q+4);
                }
                bool act = (k0+grp) < cnt;
                int o = (sv>>17)&3;
                const float* wq = wbase + o*128 + ln*8;
                float4 wA = *(const float4*)wq, wB = *(const float4*)(wq+4);
                float d = hA.x*wA.x + hA.y*wA.y + hA.z*wA.z + hA.w*wA.w
                        + hB.x*wB.x + hB.y*wB.y + hB.z*wB.z + hB.w*wB.w;
                d = qsum(d);
                float wg = act ? __expf(d + ((o==0)?bs0:((o==1)?bs1:bs2))) : 0.f;
                ssum += wg;
                fa |= (int)(act && (o==0)); fb |= (int)(act && (o==1)); fc |= (int)(act && (o==2));
                float wg0=(o==0)?wg:0.f, wg1=(o==1)?wg:0.f, wg2=(o==2)?wg:0.f;
                #pragma unroll
                for (int j=0;j<8;j++){
                    float hj = (j==0)?hA.x:(j==1)?hA.y:(j==2)?hA.z:(j==3)?hA.w:
                               (j==4)?hB.x:(j==5)?hB.y:(j==6)?hB.z:hB.w;
                    SA[j] += wg0*hj; SB[j] += wg1*hj; SC[j] += wg2*hj;
                }
                sv = svn; hA = nA; hB = nB;
            }

            ssum += __shfl_xor(ssum, 16, 64);
            ssum += __shfl_xor(ssum, 32, 64);
            float inv = 1.f/(ssum + 1e-16f);

            int anyA = __any(fa), anyB = __any(fb), anyC = __any(fc);
            if (anyA) {
                #pragma unroll
                for (int j=0;j<8;j++){ SA[j] += __shfl_xor(SA[j],16,64); SA[j] += __shfl_xor(SA[j],32,64); }
            }
            if (anyB) {
                #pragma unroll
                for (int j=0;j<8;j++){ SB[j] += __shfl_xor(SB[j],16,64); SB[j] += __shfl_xor(SB[j],32,64); }
            }
            if (anyC) {
                #pragma unroll
                for (int j=0;j<8;j++){ SC[j] += __shfl_xor(SC[j],16,64); SC[j] += __shfl_xor(SC[j],32,64); }
            }
            float Stot[8];
            #pragma unroll
            for (int j=0;j<8;j++) Stot[j] = (SA[j]+SB[j]+SC[j])*inv;

            float p0=0.f,p1=0.f,p2=0.f,p3=0.f;
            if (anyA) {
                const float* Bp = Bm + grp*4;
                #pragma unroll
                for (int j=0;j<8;j++){
                    float4 b4 = *(const float4*)(Bp + (ln*8+j)*16);
                    float v = SA[j];
                    p0+=v*b4.x; p1+=v*b4.y; p2+=v*b4.z; p3+=v*b4.w;
                }
            }
            if (anyB) {
                const float* Bp = Bm + 2048 + grp*4;
                #pragma unroll
                for (int j=0;j<8;j++){
                    float4 b4 = *(const float4*)(Bp + (ln*8+j)*16);
                    float v = SB[j];
                    p0+=v*b4.x; p1+=v*b4.y; p2+=v*b4.z; p3+=v*b4.w;
                }
            }
            if (anyC) {
                const float* Bp = Bm + 4096 + grp*4;
                #pragma unroll
                for (int j=0;j<8;j++){
                    float4 b4 = *(const float4*)(Bp + (ln*8+j)*16);
                    float v = SC[j];
                    p0+=v*b4.x; p1+=v*b4.y; p2+=v*b4.z; p3+=v*b4.w;
                }
            }
            p0 = qsum(p0)*inv; p1 = qsum(p1)*inv; p2 = qsum(p2)*inv; p3 = qsum(p3)*inv;

            int loff = (T==2) ? 3200000 : 4816000;
            if (ln < 4) {
                float v = (ln==0)?p0:((ln==1)?p1:((ln==2)?p2:p3));
                Lb[loff + (size_t)n0*16 + grp*4 + ln] = v;
            }
            if (grp == 0) {
                float* Srow = Sout + (size_t)outRow*D + ln*8;
                *(float4*)Srow     = make_float4(Stot[0],Stot[1],Stot[2],Stot[3]);
                *(float4*)(Srow+4) = make_float4(Stot[4],Stot[5],Stot[6],Stot[7]);
            }
        }
    }
}

// ---------------- K4 (fused): agg = W_base@S + sum A[p]@L_p, LN+ELU+residual ----------
__global__ __launch_bounds__(512, 1) void k4_final(Ptrs P,
        const float* __restrict__ WbT, const float* __restrict__ AT,
        const float* __restrict__ Lb,
        const float* __restrict__ gamma, const float* __restrict__ lbeta,
        float* __restrict__ out)
{
    __shared__ float st[128*132];   // S tile, stride 132
    __shared__ float wt[128*128];   // WbT tile: wt[i*128 + j]
    __shared__ float lt[128*52];    // L tile: lt[r*52 + pi*16 + k]
    int t = threadIdx.x;
    int b = blockIdx.x;
    int T, lb;
    if (b < K4_BU)      { T=0; lb=b; }
    else if (b < K4_BP) { T=1; lb=b-K4_BU; }
    else if (b < K4_BC) { T=2; lb=b-K4_BP; }
    else                { T=3; lb=b-K4_BC; }
    int r0 = lb*128;
    int rowStart = (T==0)?0:((T==1)?100000:((T==2)?200000:201000));
    int nRows    = (T==0)?NU:((T==1)?NP:((T==2)?NC:NB));
    const float* x = P.x[T];
    int nPairs = g_nGrp[T];

    for (int idx=t; idx<4096; idx+=512)
        *(float4*)&wt[idx*4] = *(const float4*)&WbT[idx*4];
    for (int idx=t; idx<4096; idx+=512){
        int r = idx>>5, i4 = idx&31;
        int lr = r0 + r;
        float4 v = (lr < nRows) ? *(const float4*)&out[(size_t)(rowStart+lr)*D + i4*4]
                                : make_float4(0.f,0.f,0.f,0.f);
        *(float4*)&st[r*132 + i4*4] = v;
    }
    for (int pi=0; pi<nPairs; ++pi){
        int lo = g_Loff[T][pi];
        int r = t>>2, q = t&3;
        int lr = r0 + r;
        float4 v = (lr < nRows) ? *(const float4*)&Lb[lo + (size_t)lr*16 + q*4]
                                : make_float4(0.f,0.f,0.f,0.f);
        *(float4*)&lt[r*52 + pi*16 + q*4] = v;
    }
    __syncthreads();

    int cg = t & 15, rg = t >> 4;
    float acc[4][8];
    #pragma unroll
    for (int a=0;a<4;a++)
        #pragma unroll
        for (int c=0;c<8;c++) acc[a][c]=0.f;

    for (int i4=0; i4<32; ++i4){
        float4 sv0 = *(const float4*)&st[(rg*4+0)*132 + i4*4];
        float4 sv1 = *(const float4*)&st[(rg*4+1)*132 + i4*4];
        float4 sv2 = *(const float4*)&st[(rg*4+2)*132 + i4*4];
        float4 sv3 = *(const float4*)&st[(rg*4+3)*132 + i4*4];
        #pragma unroll
        for (int q=0;q<4;q++){
            float4 wA = *(const float4*)&wt[(i4*4+q)*128 + cg*4];
            float4 wB = *(const float4*)&wt[(i4*4+q)*128 + 64 + cg*4];
            float sq[4];
            sq[0] = (q==0)?sv0.x:(q==1)?sv0.y:(q==2)?sv0.z:sv0.w;
            sq[1] = (q==0)?sv1.x:(q==1)?sv1.y:(q==2)?sv1.z:sv1.w;
            sq[2] = (q==0)?sv2.x:(q==1)?sv2.y:(q==2)?sv2.z:sv2.w;
            sq[3] = (q==0)?sv3.x:(q==1)?sv3.y:(q==2)?sv3.z:sv3.w;
            #pragma unroll
            for (int rr=0;rr<4;rr++){
                acc[rr][0] += sq[rr]*wA.x;
                acc[rr][1] += sq[rr]*wA.y;
                acc[rr][2] += sq[rr]*wA.z;
                acc[rr][3] += sq[rr]*wA.w;
                acc[rr][4] += sq[rr]*wB.x;
                acc[rr][5] += sq[rr]*wB.y;
                acc[rr][6] += sq[rr]*wB.z;
                acc[rr][7] += sq[rr]*wB.w;
            }
        }
    }

    for (int pi=0; pi<nPairs; ++pi){
        int ai = g_ai[T][pi];
        const float* Ap = AT + ai*2048;
        #pragma unroll 4
        for (int r=0;r<16;++r){
            float4 aA = *(const float4*)&Ap[r*128 + cg*4];
            float4 aB = *(const float4*)&Ap[r*128 + 64 + cg*4];
            float lv[4];
            #pragma unroll
            for (int rr=0;rr<4;rr++) lv[rr] = lt[(rg*4+rr)*52 + pi*16 + r];
            #pragma unroll
            for (int rr=0;rr<4;rr++){
                acc[rr][0] += lv[rr]*aA.x;
                acc[rr][1] += lv[rr]*aA.y;
                acc[rr][2] += lv[rr]*aA.z;
                acc[rr][3] += lv[rr]*aA.w;
                acc[rr][4] += lv[rr]*aB.x;
                acc[rr][5] += lv[rr]*aB.y;
                acc[rr][6] += lv[rr]*aB.z;
                acc[rr][7] += lv[rr]*aB.w;
            }
        }
    }

    int jA = cg*4, jB = 64 + cg*4;
    float4 gA = *(const float4*)&gamma[jA], gB = *(const float4*)&gamma[jB];
    float4 bA = *(const float4*)&lbeta[jA], bB = *(const float4*)&lbeta[jB];
    float gv[8] = {gA.x,gA.y,gA.z,gA.w,gB.x,gB.y,gB.z,gB.w};
    float bv[8] = {bA.x,bA.y,bA.z,bA.w,bB.x,bB.y,bB.z,bB.w};

    #pragma unroll
    for (int rr=0;rr<4;rr++){
        int lr = r0 + rg*4 + rr;
        float lsum=0.f, lsq=0.f;
        #pragma unroll
        for (int c=0;c<8;c++){ lsum += acc[rr][c]; lsq += acc[rr][c]*acc[rr][c]; }
        #pragma unroll
        for (int mm=1; mm<16; mm<<=1){ lsum += __shfl_xor(lsum,mm,64); lsq += __shfl_xor(lsq,mm,64); }
        if (lr >= nRows) continue;
        float mu = lsum*(1.f/128.f);
        float var = lsq*(1.f/128.f) - mu*mu;
        float rstd = rsqrtf(var + 1e-5f);
        const float* xr = x + (size_t)lr*D;
        float4 xA = *(const float4*)(xr+jA), xB = *(const float4*)(xr+jB);
        float xv[8] = {xA.x,xA.y,xA.z,xA.w,xB.x,xB.y,xB.z,xB.w};
        float ov[8];
        #pragma unroll
        for (int c=0;c<8;c++){
            float hn = (acc[rr][c]-mu)*rstd*gv[c] + bv[c];
            float z = hn + xv[c];
            ov[c] = z > 0.f ? z : expm1f(z);
        }
        float* orow = out + (size_t)(rowStart+lr)*D;
        *(float4*)(orow+jA) = make_float4(ov[0],ov[1],ov[2],ov[3]);
        *(float4*)(orow+jB) = make_float4(ov[4],ov[5],ov[6],ov[7]);
    }
}

extern "C" void kernel_launch(void* const* d_in, const int* in_sizes, int n_in,
                              void* d_out, int out_size, void* d_ws, size_t ws_size,
                              hipStream_t stream)
{
    (void)in_sizes; (void)n_in; (void)out_size; (void)ws_size;
    Ptrs P;
    P.x[0] = (const float*)d_in[0];   // x_user
    P.x[1] = (const float*)d_in[1];   // x_product
    P.x[2] = (const float*)d_in[2];   // x_category
    P.x[3] = (const float*)d_in[3];   // x_brand
    P.ei[0] = (const int*)d_in[4];    // view
    P.ei[1] = (const int*)d_in[5];    // cart
    P.ei[2] = (const int*)d_in[6];    // purchase
    P.ei[3] = (const int*)d_in[7];    // rev_view
    P.ei[4] = (const int*)d_in[8];    // rev_cart
    P.ei[5] = (const int*)d_in[9];    // rev_purchase
    P.ei[6] = (const int*)d_in[10];   // belongs_to
    P.attr[0] = (const int*)d_in[11];
    P.ei[7] = (const int*)d_in[12];   // contains
    P.attr[1] = (const int*)d_in[13];
    P.ei[8] = (const int*)d_in[14];   // producedBy
    P.attr[2] = (const int*)d_in[15];
    P.ei[9] = (const int*)d_in[16];   // brands
    P.attr[3] = (const int*)d_in[17];
    const float* Wb    = (const float*)d_in[18];
    const float* A     = (const float*)d_in[19];
    const float* B     = (const float*)d_in[20];
    const float* behW  = (const float*)d_in[22];
    const float* a_att = (const float*)d_in[23];
    const float* gamma = (const float*)d_in[24];
    const float* lbeta = (const float*)d_in[25];
    float* wsf = (float*)d_ws;
    float* out = (float*)d_out;

    int* ip     = (int*)(wsf + OFF_INT);
    int* counts = ip;
    int* starts = ip + 803000;
    int* srco   = ip + 1606000;
    int* bsums  = (int*)wsf;          // overlays product L-group0 (fully rewritten by kagg_beh)

    hipMemsetAsync(counts, 0, (size_t)NSEG*sizeof(int), stream);
    // zero only L regions that may be skipped (product structural groups)
    hipMemsetAsync(wsf + 3216000, 0, (size_t)(6448000-3216000)*sizeof(float), stream);

    k0_tables<<<1, 256, 0, stream>>>(Wb, A, B, behW, a_att, wsf+OFF_W0, wsf+OFF_BS);
    ktrans<<<96, 256, 0, stream>>>(Wb, A, wsf+OFF_WT, wsf+OFF_AT);
    khist<<<3125, 256, 0, stream>>>(P, counts);
    kscan1<<<NBLK, 256, 0, stream>>>(counts, starts, bsums);
    kscan2<<<1, 256, 0, stream>>>(bsums);
    kscan3<<<NBLK, 256, 0, stream>>>(starts, bsums);
    kscatter<<<3125, 256, 0, stream>>>(P, starts, srco);

    kagg_beh<<<4096, 256, 0, stream>>>(P, starts, counts, srco,
                                       wsf+OFF_W0, B, out, wsf+OFF_L, 4096*4);
    kagg_str<<<1024, 256, 0, stream>>>(P, starts, counts, srco,
                                       wsf+OFF_W0, wsf+OFF_BS, B, out, wsf+OFF_L, 1024*4);

    k4_final<<<K4_BT, 512, 0, stream>>>(P, wsf+OFF_WT, wsf+OFF_AT, wsf+OFF_L,
                                        gamma, lbeta, out);
}